// Round 10
// baseline (53.015 us; speedup 1.0000x reference)
//
#include <hip/hip_runtime.h>
#include <math.h>

#define NRAYS 8192

typedef __attribute__((ext_vector_type(8))) short bf16x8;
typedef __attribute__((ext_vector_type(4))) float f32x4;
typedef __attribute__((ext_vector_type(4))) unsigned u32x4;

#define FENCE asm volatile("" ::: "memory")

__device__ __forceinline__ short f2bf(float f) {
  union { float f; unsigned u; } v; v.f = f;
  unsigned r = (v.u + 0x7FFFu + ((v.u >> 16) & 1u)) >> 16;
  return (short)r;
}
__device__ __forceinline__ float bf2f(short s) {
  union { unsigned u; float f; } v; v.u = ((unsigned)(unsigned short)s) << 16;
  return v.f;
}
// HW packed f32->bf16 (RNE): dst = {lo=bf16(a), hi=bf16(b)}
__device__ __forceinline__ unsigned cvt2(float a, float b) {
  unsigned r;
  asm("v_cvt_pk_bf16_f32 %0, %1, %2" : "=v"(r) : "v"(a), "v"(b));
  return r;
}
__device__ __forceinline__ unsigned cvtr(float a, float b) {  // relu + pack
  return cvt2(fmaxf(a, 0.f), fmaxf(b, 0.f));
}
__device__ __forceinline__ float fast_rcp(float x) {
  float r;
  asm("v_rcp_f32 %0, %1" : "=v"(r) : "v"(x));
  return r;
}
__device__ __forceinline__ bf16x8 pack_b(unsigned a, unsigned b, unsigned c, unsigned d) {
  union { u32x4 u; bf16x8 v; } x;
  x.u = (u32x4){a, b, c, d};
  return x.v;
}
__device__ __forceinline__ float readlane63(float v) {
  return __int_as_float(__builtin_amdgcn_readlane(__float_as_int(v), 63));
}
// coarse z formula — single definition (bit-exact reuse everywhere)
__device__ __forceinline__ float zcoarse(float nearv, float span, int m) {
  return fmaf(span, (float)m * (1.f / 63.f), nearv);
}

// ------------- DPP wave64 primitives via update_dpp (ROW-scoped ctrls only —
// proven on gfx950 in round 7)
#define UPD(OLD, SRC, CTRL, RMASK)                                        \
  __int_as_float(__builtin_amdgcn_update_dpp(                             \
      __float_as_int(OLD), __float_as_int(SRC), CTRL, RMASK, 0xf, false))

__device__ __forceinline__ float scan_mul_dpp(float v) {
  v *= UPD(1.f, v, 0x111, 0xf);  // row_shr:1
  v *= UPD(1.f, v, 0x112, 0xf);  // row_shr:2
  v *= UPD(1.f, v, 0x114, 0xf);  // row_shr:4
  v *= UPD(1.f, v, 0x118, 0xf);  // row_shr:8
  v *= UPD(1.f, v, 0x142, 0xa);  // row_bcast:15 -> rows 1,3
  v *= UPD(1.f, v, 0x143, 0xc);  // row_bcast:31 -> rows 2,3
  return v;
}
__device__ __forceinline__ float scan_add_dpp(float v) {
  v += UPD(0.f, v, 0x111, 0xf);
  v += UPD(0.f, v, 0x112, 0xf);
  v += UPD(0.f, v, 0x114, 0xf);
  v += UPD(0.f, v, 0x118, 0xf);
  v += UPD(0.f, v, 0x142, 0xa);
  v += UPD(0.f, v, 0x143, 0xc);
  return v;
}
// Reduction: butterfly within rows, then cross-row bcast; total on lane 63.
__device__ __forceinline__ float red_add_dpp(float v) {
  v += UPD(0.f, v, 0xB1, 0xf);   // quad_perm [1,0,3,2]
  v += UPD(0.f, v, 0x4E, 0xf);   // quad_perm [2,3,0,1]
  v += UPD(0.f, v, 0x141, 0xf);  // row_half_mirror
  v += UPD(0.f, v, 0x140, 0xf);  // row_mirror
  v += UPD(0.f, v, 0x142, 0xa);  // row_bcast:15
  v += UPD(0.f, v, 0x143, 0xc);  // row_bcast:31
  return v;  // full sum valid on lane 63
}

// ---------------- weight fragment packing (64 threads — round-7 proven) -----
// pk (shorts): A1 @0 [4m][64][8] | A2 @2048 [2kt][64][8] | CA @3072 [4m][64][8]
//              C2A @5120 [2kt][64][8]
// GEMM2 A-frags use k-permutation: elem (kt,g,i) <-> nu = 32kt+16(i>>2)+4g+(i&3)
// Color GEMM1 k-map: k0=sigma(ignored,0) k1-15=geo ch1-15 (Wc1 rows 3..17),
//                    k16-18=dir (Wc1 rows 0..2), k19=bc1, k>=20: 0
__global__ void pack_weights(const float* __restrict__ Wd1, const float* __restrict__ bd1,
                             const float* __restrict__ Wd2, const float* __restrict__ Wc1,
                             const float* __restrict__ bc1, const float* __restrict__ Wc2,
                             short* __restrict__ pk) {
  const int l = threadIdx.x;  // 64 threads
  const int g = l >> 4, c = l & 15;
  // density GEMM1 A: xvec = [xh,yh,zh,th | xlo,ylo,zlo,tlo], g1 slot4 = bias
  for (int m = 0; m < 4; ++m) {
    int nu = 16 * m + c;
    short e[8] = {0, 0, 0, 0, 0, 0, 0, 0};
    if (g == 0) {
      for (int i = 0; i < 4; ++i) {
        short h = f2bf(Wd1[i * 64 + nu]);
        e[i] = h;
        e[4 + i] = h;
      }
    } else if (g == 1) {
      for (int i = 0; i < 4; ++i) {
        float w = Wd1[i * 64 + nu];
        e[i] = f2bf(w - bf2f(f2bf(w)));
      }
      e[4] = f2bf(bd1[nu]);
    }
    for (int i = 0; i < 8; ++i) pk[m * 512 + l * 8 + i] = e[i];
  }
  // density GEMM2 A (k-permuted)
  for (int kt = 0; kt < 2; ++kt)
    for (int i = 0; i < 8; ++i) {
      int nu = 32 * kt + 16 * (i >> 2) + 4 * g + (i & 3);
      pk[2048 + kt * 512 + l * 8 + i] = f2bf(Wd2[nu * 16 + c]);
    }
  // color GEMM1 A
  for (int m = 0; m < 4; ++m) {
    int nu = 16 * m + c;
    for (int i = 0; i < 8; ++i) {
      int k = 8 * g + i;
      short e = 0;
      if (k >= 1 && k <= 15) e = f2bf(Wc1[(2 + k) * 64 + nu]);
      else if (k >= 16 && k <= 18) e = f2bf(Wc1[(k - 16) * 64 + nu]);
      else if (k == 19) e = f2bf(bc1[nu]);
      pk[3072 + m * 512 + l * 8 + i] = e;
    }
  }
  // color GEMM2 A (k-permuted)
  for (int kt = 0; kt < 2; ++kt)
    for (int i = 0; i < 8; ++i) {
      int nu = 32 * kt + 16 * (i >> 2) + 4 * g + (i & 3);
      pk[5120 + kt * 512 + l * 8 + i] = (c < 3) ? f2bf(Wc2[nu * 3 + c]) : (short)0;
    }
}

// ---------------- density pass: MFMA, H entirely in registers ----------------
// Writes channels 4g..4g+3 to Xc cols 4g..4g+3 (branch-free, aligned b32 x2).
// Returns raw sigma (channel 0) for the owning lane.
__device__ __forceinline__ float density_pass(
    const short* __restrict__ pk, short* __restrict__ Xd, short* __restrict__ Xc,
    int lane, int g, int c, float x, float y, float z, float tf, float tLoF,
    const float* __restrict__ bd2g, int xcBase) {
  // 1. pack per-sample input [xh,yh,zh,th | xlo,ylo,zlo,tlo]
  {
    unsigned w0 = cvt2(x, y);
    unsigned w1 = cvt2(z, tf);
    union { unsigned u; float f; } ux, uy, uz;
    ux.u = w0 << 16; uy.u = w0 & 0xFFFF0000u; uz.u = w1 << 16;
    unsigned w2 = cvt2(x - ux.f, y - uy.f);
    unsigned w3 = cvt2(z - uz.f, tLoF);
    u32x4 pv; pv[0] = w0; pv[1] = w1; pv[2] = w2; pv[3] = w3;
    *(u32x4*)&Xd[lane * 8] = pv;
  }
  FENCE;

  bf16x8 A1[4];
#pragma unroll
  for (int m = 0; m < 4; ++m) A1[m] = *(const bf16x8*)(pk + m * 512 + lane * 8);

  // 2. GEMM1 (two m-halves) -> relu -> in-register B-frags P[kt][n][word]
  unsigned P[2][4][4];
#pragma unroll
  for (int mh = 0; mh < 2; ++mh) {
    f32x4 a0[4], a1[4];
#pragma unroll
    for (int n = 0; n < 4; ++n) {
      a0[n] = (f32x4){0.f, 0.f, 0.f, 0.f};
      a1[n] = (f32x4){0.f, 0.f, 0.f, 0.f};
    }
#pragma unroll
    for (int n = 0; n < 4; ++n) {
      bf16x8 v = *(const bf16x8*)&Xd[(16 * n + c) * 8];
      if (g == 1) v[4] = (short)0x3F80;  // bias slot k=12 -> 1.0
      a0[n] = __builtin_amdgcn_mfma_f32_16x16x32_bf16(A1[2 * mh], v, a0[n], 0, 0, 0);
      a1[n] = __builtin_amdgcn_mfma_f32_16x16x32_bf16(A1[2 * mh + 1], v, a1[n], 0, 0, 0);
    }
#pragma unroll
    for (int n = 0; n < 4; ++n) {
      P[mh][n][0] = cvtr(a0[n][0], a0[n][1]);
      P[mh][n][1] = cvtr(a0[n][2], a0[n][3]);
      P[mh][n][2] = cvtr(a1[n][0], a1[n][1]);
      P[mh][n][3] = cvtr(a1[n][2], a1[n][3]);
    }
  }

  // 3. GEMM2 straight from registers (k-permuted A2 matches P layout)
  bf16x8 A2[2];
  A2[0] = *(const bf16x8*)(pk + 2048 + lane * 8);
  A2[1] = *(const bf16x8*)(pk + 2048 + 512 + lane * 8);
  f32x4 o[4];
#pragma unroll
  for (int n = 0; n < 4; ++n) o[n] = (f32x4){0.f, 0.f, 0.f, 0.f};
#pragma unroll
  for (int n = 0; n < 4; ++n)
#pragma unroll
    for (int kt = 0; kt < 2; ++kt)
      o[n] = __builtin_amdgcn_mfma_f32_16x16x32_bf16(
          A2[kt], pack_b(P[kt][n][0], P[kt][n][1], P[kt][n][2], P[kt][n][3]), o[n], 0, 0, 0);

  // 4. epilogue: +bd2; channels 4g..4g+3 -> cols 4g..4g+3 (uniform, aligned)
  const float4 bd2v = *(const float4*)&bd2g[4 * g];
#pragma unroll
  for (int n = 0; n < 4; ++n) {
    o[n][0] += bd2v.x; o[n][1] += bd2v.y; o[n][2] += bd2v.z; o[n][3] += bd2v.w;
  }
#pragma unroll
  for (int n = 0; n < 4; ++n) {
    short* xr = Xc + (xcBase + 16 * n + c) * 16 + 4 * g;
    *(unsigned*)(xr + 0) = cvt2(o[n][0], o[n][1]);
    *(unsigned*)(xr + 2) = cvt2(o[n][2], o[n][3]);
  }
  FENCE;
  float t0 = __shfl(o[0][0], c);
  float t1 = __shfl(o[1][0], c);
  float t2 = __shfl(o[2][0], c);
  float t3 = __shfl(o[3][0], c);
  return (g == 0) ? t0 : (g == 1) ? t1 : (g == 2) ? t2 : t3;
}

// ---------------- main renderer: 1 ray = 1 wave = 1 block ------------------
__global__ __launch_bounds__(64, 7) void nerf_render(
    const float* __restrict__ rays_o, const float* __restrict__ rays_d,
    const float* __restrict__ time_p, const float* __restrict__ bg,
    const float* __restrict__ bd2g, const float* __restrict__ bc2g,
    const short* __restrict__ pk, float* __restrict__ out) {
  // 5120B shared. Xd (density passes) overlays zs/ss (merge onward) —
  // disjoint lifetimes, FENCE-separated.
  __shared__ __align__(64) char smem[5120];
  short* Xc  = (short*)smem;            // [0,4096)    128 rows x 32B
  short* Xd  = (short*)(smem + 4096);   // [4096,5120) 64 x 16B  (density passes)
  float* zsl = (float*)(smem + 4096);   // [4096,4608) 128 f32   (merge onward)
  float* ssl = (float*)(smem + 4608);   // [4608,5120) 128 f32

  const int lane = threadIdx.x;
  const int g = lane >> 4, c = lane & 15;
  const int ray = blockIdx.x;

  const float tf = time_p[0];
  union { unsigned u; float f; } th; th.u = cvt2(tf, tf) << 16;
  const float tLoF = tf - th.f;
  const float o0 = rays_o[ray * 3 + 0], o1 = rays_o[ray * 3 + 1], o2 = rays_o[ray * 3 + 2];
  const float d0 = rays_d[ray * 3 + 0], d1 = rays_d[ray * 3 + 1], d2 = rays_d[ray * 3 + 2];

  // ---- near / far from aabb [-1,1]^3 ----
  float nearv, farv;
  {
    float i0 = fast_rcp((fabsf(d0) < 1e-9f) ? 1e-9f : d0);
    float i1 = fast_rcp((fabsf(d1) < 1e-9f) ? 1e-9f : d1);
    float i2 = fast_rcp((fabsf(d2) < 1e-9f) ? 1e-9f : d2);
    float a0 = (-1.f - o0) * i0, b0 = (1.f - o0) * i0;
    float a1 = (-1.f - o1) * i1, b1 = (1.f - o1) * i1;
    float a2 = (-1.f - o2) * i2, b2 = (1.f - o2) * i2;
    float tmin = fmaxf(fmaxf(fminf(a0, b0), fminf(a1, b1)), fminf(a2, b2));
    float tmax = fminf(fminf(fmaxf(a0, b0), fmaxf(a1, b1)), fmaxf(a2, b2));
    nearv = fmaxf(tmin, 0.05f);
    farv = (tmax < nearv) ? (nearv + 1e-2f) : tmax;
  }
  const float span = farv - nearv;
  const float sd = span * (1.f / 64.f);

  // ---- coarse pass ----
  const float zi = zcoarse(nearv, span, lane);
  float cx = fminf(fmaxf(fmaf(d0, zi, o0), -1.f), 1.f);
  float cy = fminf(fmaxf(fmaf(d1, zi, o1), -1.f), 1.f);
  float cz = fminf(fmaxf(fmaf(d2, zi, o2), -1.f), 1.f);
  float sraw = density_pass(pk, Xd, Xc, lane, g, c, cx, cy, cz, tf, tLoF, bd2g, 0);
  const float sigma = __expf(sraw);

  // ---- coarse compositing -> cdf (registers; shfl for +-1 lane) ----
  float cdfS;
  {
    const float znext = __shfl_down(zi, 1, 64);
    const float cdelta = (lane < 63) ? (znext - zi) : sd;
    const float calpha = 1.f - __expf(-cdelta * sigma);
    float T = 1.f - calpha + 1e-15f;
    float Pincl = scan_mul_dpp(T);
    float Pexcl = __shfl_up(Pincl, 1, 64);
    if (lane == 0) Pexcl = 1.f;
    float wgt = calpha * Pexcl;
    float v = (lane >= 1 && lane <= 62) ? (wgt + 1e-5f) : 0.f;
    float S = scan_add_dpp(v);
    cdfS = S * fast_rcp(readlane63(S));  // cdf[lane]; lane0=0
  }

  // ---- inverse-CDF resampling (register shfl search, bins analytic) ----
  // range 63 -> 64 outcomes -> 6 probes suffice.
  float nzv;
  {
    const float u = ((float)lane + 0.5f) * 0.015625f;
    int lo = 0, hi = 63;
#pragma unroll
    for (int it = 0; it < 6; ++it) {  // fixed trip: uniform exec for shfl
      int mid = (lo + hi) >> 1;
      float v = __shfl(cdfS, mid, 64);
      if (lo < hi) { if (v <= u) lo = mid + 1; else hi = mid; }
    }
    int below = lo - 1;                 // lo>=1 (cdf[0]=0 <= u always)
    int above = (lo < 62) ? lo : 62;
    float c0 = __shfl(cdfS, below, 64);
    float c1 = __shfl(cdfS, above, 64);
    float b0 = 0.5f * (zcoarse(nearv, span, below) + zcoarse(nearv, span, below + 1));
    float b1 = 0.5f * (zcoarse(nearv, span, above) + zcoarse(nearv, span, above + 1));
    float dn = c1 - c0;
    dn = (dn < 1e-5f) ? 1.f : dn;
    nzv = fmaf((u - c0) * fast_rcp(dn), (b1 - b0), b0);
  }

  // ---- fine pass ----
  float fx = fminf(fmaxf(fmaf(d0, nzv, o0), -1.f), 1.f);
  float fy = fminf(fmaxf(fmaf(d1, nzv, o1), -1.f), 1.f);
  float fz = fminf(fmaxf(fmaf(d2, nzv, o2), -1.f), 1.f);
  float nsraw = density_pass(pk, Xd, Xc, lane, g, c, fx, fy, fz, tf, tLoF, bd2g, 64);
  const float nsigma = __expf(nsraw);
  FENCE;

  // ---- stable-merge ranks (range 64 -> 65 outcomes -> SEVEN probes) ----
  int r1, r2;
  {
    int lo = 0, hi = 64;
#pragma unroll
    for (int it = 0; it < 7; ++it) {  // 7: ceil(log2(65)) — round-8/9 bug was 6
      int mid = (lo + hi) >> 1;
      float v = __shfl(nzv, mid, 64);
      if (lo < hi) { if (v < zi) lo = mid + 1; else hi = mid; }
    }
    r1 = lane + lo;
  }
  {
    int lo = 0, hi = 64;
#pragma unroll
    for (int it = 0; it < 7; ++it) {
      int mid = (lo + hi) >> 1;
      if (lo < hi) { if (zcoarse(nearv, span, mid) <= nzv) lo = mid + 1; else hi = mid; }
    }
    r2 = lane + lo;
  }
  // Xd is dead from here; zs/ss overlay it.
  FENCE;
  zsl[r1] = zi;  ssl[r1] = sigma;
  zsl[r2] = nzv; ssl[r2] = nsigma;
  FENCE;

  // ---- composite over 128 sorted samples (DPP scans; weights in registers) --
  float w0, w1, wsum;
  {
    float z0 = zsl[lane];
    float z0n = zsl[lane + 1];
    float z1 = zsl[lane + 64];
    float dl0 = z0n - z0;
    float dl1 = (lane < 63) ? (zsl[lane + 65] - z1) : sd;
    float al0 = 1.f - __expf(-dl0 * ssl[lane]);
    float al1 = 1.f - __expf(-dl1 * ssl[lane + 64]);
    float T0 = 1.f - al0 + 1e-15f;
    float T1 = 1.f - al1 + 1e-15f;
    float P0 = scan_mul_dpp(T0);
    float P1 = scan_mul_dpp(T1);
    float prodLo = readlane63(P0);
    float e0 = __shfl_up(P0, 1, 64);
    float e1 = __shfl_up(P1, 1, 64);
    if (lane == 0) { e0 = 1.f; e1 = 1.f; }
    w0 = al0 * e0;
    w1 = al1 * prodLo * e1;
    wsum = red_add_dpp(w0 + w1);  // valid on lane 63
  }

  // ---- weights back in unmerged order via shfl (uniform exec) ----
  float wlo = __shfl(w0, r1 & 63, 64);
  float whi = __shfl(w1, r1 & 63, 64);
  const float wc = (r1 < 64) ? wlo : whi;
  wlo = __shfl(w0, r2 & 63, 64);
  whi = __shfl(w1, r2 & 63, 64);
  const float wf = (r2 < 64) ? wlo : whi;
  const unsigned long long mC = __ballot(wc > 1e-4f);
  const unsigned long long mF = __ballot(wf > 1e-4f);

  // ---- color MLP: H in registers; dir+bias from g==2 register operand ----
  bf16x8 CA[4];
#pragma unroll
  for (int m = 0; m < 4; ++m) CA[m] = *(const bf16x8*)(pk + 3072 + m * 512 + lane * 8);
  bf16x8 C2A[2];
  C2A[0] = *(const bf16x8*)(pk + 5120 + lane * 8);
  C2A[1] = *(const bf16x8*)(pk + 5120 + 512 + lane * 8);
  const float bc20 = bc2g[0], bc21 = bc2g[1], bc22 = bc2g[2];
  const bf16x8 bD = pack_b(cvt2(d0, d1), cvt2(d2, 1.0f), 0u, 0u);  // k16-19: d,1.0
  const bf16x8 bZ = pack_b(0u, 0u, 0u, 0u);
  const int xoffs = (g < 2) ? 8 * g : 0;

  float cr = 0.f, cgr = 0.f, cb = 0.f;
#pragma unroll
  for (int half = 0; half < 2; ++half) {
    const unsigned long long mm = half ? mF : mC;
    const float wcf = half ? wf : wc;
#pragma unroll
    for (int n = 0; n < 4; ++n) {
      if ((mm >> (16 * n)) & 0xFFFFull) {  // wave-uniform branch
        float wgt = __shfl(wcf, 16 * n + c, 64);  // uniform exec
        bf16x8 ld = *(const bf16x8*)&Xc[(64 * half + 16 * n + c) * 16 + xoffs];
        bf16x8 V = (g < 2) ? ld : ((g == 2) ? bD : bZ);
        f32x4 a[4];
#pragma unroll
        for (int m = 0; m < 4; ++m) {
          a[m] = (f32x4){0.f, 0.f, 0.f, 0.f};
          a[m] = __builtin_amdgcn_mfma_f32_16x16x32_bf16(CA[m], V, a[m], 0, 0, 0);
        }
        f32x4 oc = (f32x4){0.f, 0.f, 0.f, 0.f};
#pragma unroll
        for (int kt = 0; kt < 2; ++kt) {
          bf16x8 Bh = pack_b(cvtr(a[2 * kt][0], a[2 * kt][1]),
                             cvtr(a[2 * kt][2], a[2 * kt][3]),
                             cvtr(a[2 * kt + 1][0], a[2 * kt + 1][1]),
                             cvtr(a[2 * kt + 1][2], a[2 * kt + 1][3]));
          oc = __builtin_amdgcn_mfma_f32_16x16x32_bf16(C2A[kt], Bh, oc, 0, 0, 0);
        }
        if (g == 0 && wgt > 1e-4f) {
          cr  += wgt * fast_rcp(1.f + __expf(-(oc[0] + bc20)));
          cgr += wgt * fast_rcp(1.f + __expf(-(oc[1] + bc21)));
          cb  += wgt * fast_rcp(1.f + __expf(-(oc[2] + bc22)));
        }
      }
    }
  }

  cr = red_add_dpp(cr);
  cgr = red_add_dpp(cgr);
  cb = red_add_dpp(cb);

  if (lane == 63) {  // reductions land on lane 63
    const float rem = 1.f - wsum;
    out[ray * 3 + 0] = cr + rem * bg[0];
    out[ray * 3 + 1] = cgr + rem * bg[1];
    out[ray * 3 + 2] = cb + rem * bg[2];
  }
}

extern "C" void kernel_launch(void* const* d_in, const int* in_sizes, int n_in,
                              void* d_out, int out_size, void* d_ws, size_t ws_size,
                              hipStream_t stream) {
  const float* rays_o = (const float*)d_in[0];
  const float* rays_d = (const float*)d_in[1];
  const float* time_p = (const float*)d_in[2];
  const float* bg     = (const float*)d_in[3];
  const float* Wd1    = (const float*)d_in[4];
  const float* bd1    = (const float*)d_in[5];
  const float* Wd2    = (const float*)d_in[6];
  const float* bd2    = (const float*)d_in[7];
  const float* Wc1    = (const float*)d_in[8];
  const float* bc1    = (const float*)d_in[9];
  const float* Wc2    = (const float*)d_in[10];
  const float* bc2    = (const float*)d_in[11];

  short* pk = (short*)d_ws;  // 12 KiB packed weight fragments
  pack_weights<<<1, 64, 0, stream>>>(Wd1, bd1, Wd2, Wc1, bc1, Wc2, pk);
  nerf_render<<<NRAYS, 64, 0, stream>>>(rays_o, rays_d, time_p, bg, bd2, bc2, pk,
                                        (float*)d_out);
}

// Round 11
// 38.731 us; speedup vs baseline: 1.3688x; 1.3688x over previous
//
#include <hip/hip_runtime.h>
#include <math.h>

#define NRAYS 8192

typedef __attribute__((ext_vector_type(8))) short bf16x8;
typedef __attribute__((ext_vector_type(4))) float f32x4;
typedef __attribute__((ext_vector_type(4))) unsigned u32x4;

#define FENCE asm volatile("" ::: "memory")

__device__ __forceinline__ short f2bf(float f) {
  union { float f; unsigned u; } v; v.f = f;
  unsigned r = (v.u + 0x7FFFu + ((v.u >> 16) & 1u)) >> 16;
  return (short)r;
}
__device__ __forceinline__ float bf2f(short s) {
  union { unsigned u; float f; } v; v.u = ((unsigned)(unsigned short)s) << 16;
  return v.f;
}
// HW packed f32->bf16 (RNE): dst = {lo=bf16(a), hi=bf16(b)}
__device__ __forceinline__ unsigned cvt2(float a, float b) {
  unsigned r;
  asm("v_cvt_pk_bf16_f32 %0, %1, %2" : "=v"(r) : "v"(a), "v"(b));
  return r;
}
__device__ __forceinline__ unsigned cvtr(float a, float b) {  // relu + pack
  return cvt2(fmaxf(a, 0.f), fmaxf(b, 0.f));
}
__device__ __forceinline__ float fast_rcp(float x) {
  float r;
  asm("v_rcp_f32 %0, %1" : "=v"(r) : "v"(x));
  return r;
}
__device__ __forceinline__ bf16x8 pack_b(unsigned a, unsigned b, unsigned c, unsigned d) {
  union { u32x4 u; bf16x8 v; } x;
  x.u = (u32x4){a, b, c, d};
  return x.v;
}
__device__ __forceinline__ float readlane63(float v) {
  return __int_as_float(__builtin_amdgcn_readlane(__float_as_int(v), 63));
}
// coarse z formula — single definition (bit-exact reuse everywhere)
__device__ __forceinline__ float zcoarse(float nearv, float span, int m) {
  return fmaf(span, (float)m * (1.f / 63.f), nearv);
}

// ------------- DPP wave64 primitives via update_dpp (ROW-scoped ctrls only —
// proven on gfx950 in round 7)
#define UPD(OLD, SRC, CTRL, RMASK)                                        \
  __int_as_float(__builtin_amdgcn_update_dpp(                             \
      __float_as_int(OLD), __float_as_int(SRC), CTRL, RMASK, 0xf, false))

__device__ __forceinline__ float scan_mul_dpp(float v) {
  v *= UPD(1.f, v, 0x111, 0xf);  // row_shr:1
  v *= UPD(1.f, v, 0x112, 0xf);  // row_shr:2
  v *= UPD(1.f, v, 0x114, 0xf);  // row_shr:4
  v *= UPD(1.f, v, 0x118, 0xf);  // row_shr:8
  v *= UPD(1.f, v, 0x142, 0xa);  // row_bcast:15 -> rows 1,3
  v *= UPD(1.f, v, 0x143, 0xc);  // row_bcast:31 -> rows 2,3
  return v;
}
__device__ __forceinline__ float scan_add_dpp(float v) {
  v += UPD(0.f, v, 0x111, 0xf);
  v += UPD(0.f, v, 0x112, 0xf);
  v += UPD(0.f, v, 0x114, 0xf);
  v += UPD(0.f, v, 0x118, 0xf);
  v += UPD(0.f, v, 0x142, 0xa);
  v += UPD(0.f, v, 0x143, 0xc);
  return v;
}
// Reduction: butterfly within rows, then cross-row bcast; total on lane 63.
__device__ __forceinline__ float red_add_dpp(float v) {
  v += UPD(0.f, v, 0xB1, 0xf);   // quad_perm [1,0,3,2]
  v += UPD(0.f, v, 0x4E, 0xf);   // quad_perm [2,3,0,1]
  v += UPD(0.f, v, 0x141, 0xf);  // row_half_mirror
  v += UPD(0.f, v, 0x140, 0xf);  // row_mirror
  v += UPD(0.f, v, 0x142, 0xa);  // row_bcast:15
  v += UPD(0.f, v, 0x143, 0xc);  // row_bcast:31
  return v;  // full sum valid on lane 63
}

// ---------------- weight fragment packing (64 threads — round-7 proven) -----
// pk (shorts): A1 @0 [4m][64][8] | A2 @2048 [2kt][64][8] | CA @3072 [4m][64][8]
//              C2A @5120 [2kt][64][8]
// GEMM2 A-frags use k-permutation: elem (kt,g,i) <-> nu = 32kt+16(i>>2)+4g+(i&3)
// Color GEMM1 k-map: k0=sigma(ignored,0) k1-15=geo ch1-15 (Wc1 rows 3..17),
//                    k16-18=dir (Wc1 rows 0..2), k19=bc1, k>=20: 0
__global__ void pack_weights(const float* __restrict__ Wd1, const float* __restrict__ bd1,
                             const float* __restrict__ Wd2, const float* __restrict__ Wc1,
                             const float* __restrict__ bc1, const float* __restrict__ Wc2,
                             short* __restrict__ pk) {
  const int l = threadIdx.x;  // 64 threads
  const int g = l >> 4, c = l & 15;
  // density GEMM1 A: xvec = [xh,yh,zh,th | xlo,ylo,zlo,tlo], g1 slot4 = bias
  for (int m = 0; m < 4; ++m) {
    int nu = 16 * m + c;
    short e[8] = {0, 0, 0, 0, 0, 0, 0, 0};
    if (g == 0) {
      for (int i = 0; i < 4; ++i) {
        short h = f2bf(Wd1[i * 64 + nu]);
        e[i] = h;
        e[4 + i] = h;
      }
    } else if (g == 1) {
      for (int i = 0; i < 4; ++i) {
        float w = Wd1[i * 64 + nu];
        e[i] = f2bf(w - bf2f(f2bf(w)));
      }
      e[4] = f2bf(bd1[nu]);
    }
    for (int i = 0; i < 8; ++i) pk[m * 512 + l * 8 + i] = e[i];
  }
  // density GEMM2 A (k-permuted)
  for (int kt = 0; kt < 2; ++kt)
    for (int i = 0; i < 8; ++i) {
      int nu = 32 * kt + 16 * (i >> 2) + 4 * g + (i & 3);
      pk[2048 + kt * 512 + l * 8 + i] = f2bf(Wd2[nu * 16 + c]);
    }
  // color GEMM1 A
  for (int m = 0; m < 4; ++m) {
    int nu = 16 * m + c;
    for (int i = 0; i < 8; ++i) {
      int k = 8 * g + i;
      short e = 0;
      if (k >= 1 && k <= 15) e = f2bf(Wc1[(2 + k) * 64 + nu]);
      else if (k >= 16 && k <= 18) e = f2bf(Wc1[(k - 16) * 64 + nu]);
      else if (k == 19) e = f2bf(bc1[nu]);
      pk[3072 + m * 512 + l * 8 + i] = e;
    }
  }
  // color GEMM2 A (k-permuted)
  for (int kt = 0; kt < 2; ++kt)
    for (int i = 0; i < 8; ++i) {
      int nu = 32 * kt + 16 * (i >> 2) + 4 * g + (i & 3);
      pk[5120 + kt * 512 + l * 8 + i] = (c < 3) ? f2bf(Wc2[nu * 3 + c]) : (short)0;
    }
}

// ---------------- density pass: MFMA, H entirely in registers ----------------
// Writes channels 4g..4g+3 to Xc cols 4g..4g+3 (branch-free, aligned b32 x2).
// Returns raw sigma (channel 0) for the owning lane.
__device__ __forceinline__ float density_pass(
    const short* __restrict__ pk, short* __restrict__ Xd, short* __restrict__ Xc,
    int lane, int g, int c, float x, float y, float z, float tf, float tLoF,
    const float* __restrict__ bd2g, int xcBase) {
  // 1. pack per-sample input [xh,yh,zh,th | xlo,ylo,zlo,tlo]
  {
    unsigned w0 = cvt2(x, y);
    unsigned w1 = cvt2(z, tf);
    union { unsigned u; float f; } ux, uy, uz;
    ux.u = w0 << 16; uy.u = w0 & 0xFFFF0000u; uz.u = w1 << 16;
    unsigned w2 = cvt2(x - ux.f, y - uy.f);
    unsigned w3 = cvt2(z - uz.f, tLoF);
    u32x4 pv; pv[0] = w0; pv[1] = w1; pv[2] = w2; pv[3] = w3;
    *(u32x4*)&Xd[lane * 8] = pv;
  }
  FENCE;

  bf16x8 A1[4];
#pragma unroll
  for (int m = 0; m < 4; ++m) A1[m] = *(const bf16x8*)(pk + m * 512 + lane * 8);

  // 2. GEMM1 (two m-halves) -> relu -> in-register B-frags P[kt][n][word]
  unsigned P[2][4][4];
#pragma unroll
  for (int mh = 0; mh < 2; ++mh) {
    f32x4 a0[4], a1[4];
#pragma unroll
    for (int n = 0; n < 4; ++n) {
      a0[n] = (f32x4){0.f, 0.f, 0.f, 0.f};
      a1[n] = (f32x4){0.f, 0.f, 0.f, 0.f};
    }
#pragma unroll
    for (int n = 0; n < 4; ++n) {
      bf16x8 v = *(const bf16x8*)&Xd[(16 * n + c) * 8];
      if (g == 1) v[4] = (short)0x3F80;  // bias slot k=12 -> 1.0
      a0[n] = __builtin_amdgcn_mfma_f32_16x16x32_bf16(A1[2 * mh], v, a0[n], 0, 0, 0);
      a1[n] = __builtin_amdgcn_mfma_f32_16x16x32_bf16(A1[2 * mh + 1], v, a1[n], 0, 0, 0);
    }
#pragma unroll
    for (int n = 0; n < 4; ++n) {
      P[mh][n][0] = cvtr(a0[n][0], a0[n][1]);
      P[mh][n][1] = cvtr(a0[n][2], a0[n][3]);
      P[mh][n][2] = cvtr(a1[n][0], a1[n][1]);
      P[mh][n][3] = cvtr(a1[n][2], a1[n][3]);
    }
  }

  // 3. GEMM2 straight from registers (k-permuted A2 matches P layout)
  bf16x8 A2[2];
  A2[0] = *(const bf16x8*)(pk + 2048 + lane * 8);
  A2[1] = *(const bf16x8*)(pk + 2048 + 512 + lane * 8);
  f32x4 o[4];
#pragma unroll
  for (int n = 0; n < 4; ++n) o[n] = (f32x4){0.f, 0.f, 0.f, 0.f};
#pragma unroll
  for (int n = 0; n < 4; ++n)
#pragma unroll
    for (int kt = 0; kt < 2; ++kt)
      o[n] = __builtin_amdgcn_mfma_f32_16x16x32_bf16(
          A2[kt], pack_b(P[kt][n][0], P[kt][n][1], P[kt][n][2], P[kt][n][3]), o[n], 0, 0, 0);

  // 4. epilogue: +bd2; channels 4g..4g+3 -> cols 4g..4g+3 (uniform, aligned)
  const float4 bd2v = *(const float4*)&bd2g[4 * g];
#pragma unroll
  for (int n = 0; n < 4; ++n) {
    o[n][0] += bd2v.x; o[n][1] += bd2v.y; o[n][2] += bd2v.z; o[n][3] += bd2v.w;
  }
#pragma unroll
  for (int n = 0; n < 4; ++n) {
    short* xr = Xc + (xcBase + 16 * n + c) * 16 + 4 * g;
    *(unsigned*)(xr + 0) = cvt2(o[n][0], o[n][1]);
    *(unsigned*)(xr + 2) = cvt2(o[n][2], o[n][3]);
  }
  FENCE;
  float t0 = __shfl(o[0][0], c);
  float t1 = __shfl(o[1][0], c);
  float t2 = __shfl(o[2][0], c);
  float t3 = __shfl(o[3][0], c);
  return (g == 0) ? t0 : (g == 1) ? t1 : (g == 2) ? t2 : t3;
}

// ---------------- main renderer: 1 ray = 1 wave = 1 block ------------------
__global__ __launch_bounds__(64, 4) void nerf_render(
    const float* __restrict__ rays_o, const float* __restrict__ rays_d,
    const float* __restrict__ time_p, const float* __restrict__ bg,
    const float* __restrict__ bd2g, const float* __restrict__ bc2g,
    const short* __restrict__ pk, float* __restrict__ out) {
  // 5120B shared. Xd (density passes) overlays zs/ss (merge onward) —
  // disjoint lifetimes, FENCE-separated.
  __shared__ __align__(64) char smem[5120];
  short* Xc  = (short*)smem;            // [0,4096)    128 rows x 32B
  short* Xd  = (short*)(smem + 4096);   // [4096,5120) 64 x 16B  (density passes)
  float* zsl = (float*)(smem + 4096);   // [4096,4608) 128 f32   (merge onward)
  float* ssl = (float*)(smem + 4608);   // [4608,5120) 128 f32

  const int lane = threadIdx.x;
  const int g = lane >> 4, c = lane & 15;
  const int ray = blockIdx.x;

  const float tf = time_p[0];
  union { unsigned u; float f; } th; th.u = cvt2(tf, tf) << 16;
  const float tLoF = tf - th.f;
  const float o0 = rays_o[ray * 3 + 0], o1 = rays_o[ray * 3 + 1], o2 = rays_o[ray * 3 + 2];
  const float d0 = rays_d[ray * 3 + 0], d1 = rays_d[ray * 3 + 1], d2 = rays_d[ray * 3 + 2];

  // ---- near / far from aabb [-1,1]^3 ----
  float nearv, farv;
  {
    float i0 = fast_rcp((fabsf(d0) < 1e-9f) ? 1e-9f : d0);
    float i1 = fast_rcp((fabsf(d1) < 1e-9f) ? 1e-9f : d1);
    float i2 = fast_rcp((fabsf(d2) < 1e-9f) ? 1e-9f : d2);
    float a0 = (-1.f - o0) * i0, b0 = (1.f - o0) * i0;
    float a1 = (-1.f - o1) * i1, b1 = (1.f - o1) * i1;
    float a2 = (-1.f - o2) * i2, b2 = (1.f - o2) * i2;
    float tmin = fmaxf(fmaxf(fminf(a0, b0), fminf(a1, b1)), fminf(a2, b2));
    float tmax = fminf(fminf(fmaxf(a0, b0), fmaxf(a1, b1)), fmaxf(a2, b2));
    nearv = fmaxf(tmin, 0.05f);
    farv = (tmax < nearv) ? (nearv + 1e-2f) : tmax;
  }
  const float span = farv - nearv;
  const float sd = span * (1.f / 64.f);

  // ---- coarse pass ----
  const float zi = zcoarse(nearv, span, lane);
  float cx = fminf(fmaxf(fmaf(d0, zi, o0), -1.f), 1.f);
  float cy = fminf(fmaxf(fmaf(d1, zi, o1), -1.f), 1.f);
  float cz = fminf(fmaxf(fmaf(d2, zi, o2), -1.f), 1.f);
  float sraw = density_pass(pk, Xd, Xc, lane, g, c, cx, cy, cz, tf, tLoF, bd2g, 0);
  const float sigma = __expf(sraw);

  // ---- coarse compositing -> cdf (registers; shfl for +-1 lane) ----
  float cdfS;
  {
    const float znext = __shfl_down(zi, 1, 64);
    const float cdelta = (lane < 63) ? (znext - zi) : sd;
    const float calpha = 1.f - __expf(-cdelta * sigma);
    float T = 1.f - calpha + 1e-15f;
    float Pincl = scan_mul_dpp(T);
    float Pexcl = __shfl_up(Pincl, 1, 64);
    if (lane == 0) Pexcl = 1.f;
    float wgt = calpha * Pexcl;
    float v = (lane >= 1 && lane <= 62) ? (wgt + 1e-5f) : 0.f;
    float S = scan_add_dpp(v);
    cdfS = S * fast_rcp(readlane63(S));  // cdf[lane]; lane0=0
  }

  // ---- inverse-CDF resampling (register shfl search, bins analytic) ----
  // range 63 -> 64 outcomes -> 6 probes suffice.
  float nzv;
  {
    const float u = ((float)lane + 0.5f) * 0.015625f;
    int lo = 0, hi = 63;
#pragma unroll
    for (int it = 0; it < 6; ++it) {  // fixed trip: uniform exec for shfl
      int mid = (lo + hi) >> 1;
      float v = __shfl(cdfS, mid, 64);
      if (lo < hi) { if (v <= u) lo = mid + 1; else hi = mid; }
    }
    int below = lo - 1;                 // lo>=1 (cdf[0]=0 <= u always)
    int above = (lo < 62) ? lo : 62;
    float c0 = __shfl(cdfS, below, 64);
    float c1 = __shfl(cdfS, above, 64);
    float b0 = 0.5f * (zcoarse(nearv, span, below) + zcoarse(nearv, span, below + 1));
    float b1 = 0.5f * (zcoarse(nearv, span, above) + zcoarse(nearv, span, above + 1));
    float dn = c1 - c0;
    dn = (dn < 1e-5f) ? 1.f : dn;
    nzv = fmaf((u - c0) * fast_rcp(dn), (b1 - b0), b0);
  }

  // ---- fine pass ----
  float fx = fminf(fmaxf(fmaf(d0, nzv, o0), -1.f), 1.f);
  float fy = fminf(fmaxf(fmaf(d1, nzv, o1), -1.f), 1.f);
  float fz = fminf(fmaxf(fmaf(d2, nzv, o2), -1.f), 1.f);
  float nsraw = density_pass(pk, Xd, Xc, lane, g, c, fx, fy, fz, tf, tLoF, bd2g, 64);
  const float nsigma = __expf(nsraw);
  FENCE;

  // ---- stable-merge ranks (range 64 -> 65 outcomes -> SEVEN probes) ----
  int r1, r2;
  {
    int lo = 0, hi = 64;
#pragma unroll
    for (int it = 0; it < 7; ++it) {  // 7 = ceil(log2(65))
      int mid = (lo + hi) >> 1;
      float v = __shfl(nzv, mid, 64);
      if (lo < hi) { if (v < zi) lo = mid + 1; else hi = mid; }
    }
    r1 = lane + lo;
  }
  {
    int lo = 0, hi = 64;
#pragma unroll
    for (int it = 0; it < 7; ++it) {
      int mid = (lo + hi) >> 1;
      if (lo < hi) { if (zcoarse(nearv, span, mid) <= nzv) lo = mid + 1; else hi = mid; }
    }
    r2 = lane + lo;
  }
  // Xd is dead from here; zs/ss overlay it.
  FENCE;
  zsl[r1] = zi;  ssl[r1] = sigma;
  zsl[r2] = nzv; ssl[r2] = nsigma;
  FENCE;

  // ---- composite over 128 sorted samples (DPP scans; weights in registers) --
  float w0, w1, wsum;
  {
    float z0 = zsl[lane];
    float z0n = zsl[lane + 1];
    float z1 = zsl[lane + 64];
    float dl0 = z0n - z0;
    float dl1 = (lane < 63) ? (zsl[lane + 65] - z1) : sd;
    float al0 = 1.f - __expf(-dl0 * ssl[lane]);
    float al1 = 1.f - __expf(-dl1 * ssl[lane + 64]);
    float T0 = 1.f - al0 + 1e-15f;
    float T1 = 1.f - al1 + 1e-15f;
    float P0 = scan_mul_dpp(T0);
    float P1 = scan_mul_dpp(T1);
    float prodLo = readlane63(P0);
    float e0 = __shfl_up(P0, 1, 64);
    float e1 = __shfl_up(P1, 1, 64);
    if (lane == 0) { e0 = 1.f; e1 = 1.f; }
    w0 = al0 * e0;
    w1 = al1 * prodLo * e1;
    wsum = red_add_dpp(w0 + w1);  // valid on lane 63
  }

  // ---- weights back in unmerged order via shfl (uniform exec) ----
  float wlo = __shfl(w0, r1 & 63, 64);
  float whi = __shfl(w1, r1 & 63, 64);
  const float wc = (r1 < 64) ? wlo : whi;
  wlo = __shfl(w0, r2 & 63, 64);
  whi = __shfl(w1, r2 & 63, 64);
  const float wf = (r2 < 64) ? wlo : whi;
  const unsigned long long mC = __ballot(wc > 1e-4f);
  const unsigned long long mF = __ballot(wf > 1e-4f);

  // ---- color MLP: H in registers; dir+bias from g==2 register operand ----
  bf16x8 CA[4];
#pragma unroll
  for (int m = 0; m < 4; ++m) CA[m] = *(const bf16x8*)(pk + 3072 + m * 512 + lane * 8);
  bf16x8 C2A[2];
  C2A[0] = *(const bf16x8*)(pk + 5120 + lane * 8);
  C2A[1] = *(const bf16x8*)(pk + 5120 + 512 + lane * 8);
  const float bc20 = bc2g[0], bc21 = bc2g[1], bc22 = bc2g[2];
  const bf16x8 bD = pack_b(cvt2(d0, d1), cvt2(d2, 1.0f), 0u, 0u);  // k16-19: d,1.0
  const bf16x8 bZ = pack_b(0u, 0u, 0u, 0u);
  const int xoffs = (g < 2) ? 8 * g : 0;

  float cr = 0.f, cgr = 0.f, cb = 0.f;
#pragma unroll
  for (int half = 0; half < 2; ++half) {
    const unsigned long long mm = half ? mF : mC;
    const float wcf = half ? wf : wc;
#pragma unroll
    for (int n = 0; n < 4; ++n) {
      if ((mm >> (16 * n)) & 0xFFFFull) {  // wave-uniform branch
        float wgt = __shfl(wcf, 16 * n + c, 64);  // uniform exec
        bf16x8 ld = *(const bf16x8*)&Xc[(64 * half + 16 * n + c) * 16 + xoffs];
        bf16x8 V = (g < 2) ? ld : ((g == 2) ? bD : bZ);
        f32x4 a[4];
#pragma unroll
        for (int m = 0; m < 4; ++m) {
          a[m] = (f32x4){0.f, 0.f, 0.f, 0.f};
          a[m] = __builtin_amdgcn_mfma_f32_16x16x32_bf16(CA[m], V, a[m], 0, 0, 0);
        }
        f32x4 oc = (f32x4){0.f, 0.f, 0.f, 0.f};
#pragma unroll
        for (int kt = 0; kt < 2; ++kt) {
          bf16x8 Bh = pack_b(cvtr(a[2 * kt][0], a[2 * kt][1]),
                             cvtr(a[2 * kt][2], a[2 * kt][3]),
                             cvtr(a[2 * kt + 1][0], a[2 * kt + 1][1]),
                             cvtr(a[2 * kt + 1][2], a[2 * kt + 1][3]));
          oc = __builtin_amdgcn_mfma_f32_16x16x32_bf16(C2A[kt], Bh, oc, 0, 0, 0);
        }
        if (g == 0 && wgt > 1e-4f) {
          cr  += wgt * fast_rcp(1.f + __expf(-(oc[0] + bc20)));
          cgr += wgt * fast_rcp(1.f + __expf(-(oc[1] + bc21)));
          cb  += wgt * fast_rcp(1.f + __expf(-(oc[2] + bc22)));
        }
      }
    }
  }

  cr = red_add_dpp(cr);
  cgr = red_add_dpp(cgr);
  cb = red_add_dpp(cb);

  if (lane == 63) {  // reductions land on lane 63
    const float rem = 1.f - wsum;
    out[ray * 3 + 0] = cr + rem * bg[0];
    out[ray * 3 + 1] = cgr + rem * bg[1];
    out[ray * 3 + 2] = cb + rem * bg[2];
  }
}

extern "C" void kernel_launch(void* const* d_in, const int* in_sizes, int n_in,
                              void* d_out, int out_size, void* d_ws, size_t ws_size,
                              hipStream_t stream) {
  const float* rays_o = (const float*)d_in[0];
  const float* rays_d = (const float*)d_in[1];
  const float* time_p = (const float*)d_in[2];
  const float* bg     = (const float*)d_in[3];
  const float* Wd1    = (const float*)d_in[4];
  const float* bd1    = (const float*)d_in[5];
  const float* Wd2    = (const float*)d_in[6];
  const float* bd2    = (const float*)d_in[7];
  const float* Wc1    = (const float*)d_in[8];
  const float* bc1    = (const float*)d_in[9];
  const float* Wc2    = (const float*)d_in[10];
  const float* bc2    = (const float*)d_in[11];

  short* pk = (short*)d_ws;  // 12 KiB packed weight fragments
  pack_weights<<<1, 64, 0, stream>>>(Wd1, bd1, Wd2, Wc1, bc1, Wc2, pk);
  nerf_render<<<NRAYS, 64, 0, stream>>>(rays_o, rays_d, time_p, bg, bd2, bc2, pk,
                                        (float*)d_out);
}

// Round 14
// 38.318 us; speedup vs baseline: 1.3836x; 1.0108x over previous
//
#include <hip/hip_runtime.h>
#include <math.h>

#define NRAYS 8192

typedef __attribute__((ext_vector_type(8))) short bf16x8;
typedef __attribute__((ext_vector_type(4))) float f32x4;
typedef __attribute__((ext_vector_type(4))) unsigned u32x4;

#define FENCE asm volatile("" ::: "memory")

__device__ __forceinline__ short f2bf(float f) {
  union { float f; unsigned u; } v; v.f = f;
  unsigned r = (v.u + 0x7FFFu + ((v.u >> 16) & 1u)) >> 16;
  return (short)r;
}
__device__ __forceinline__ float bf2f(short s) {
  union { unsigned u; float f; } v; v.u = ((unsigned)(unsigned short)s) << 16;
  return v.f;
}
// HW packed f32->bf16 (RNE): dst = {lo=bf16(a), hi=bf16(b)}
__device__ __forceinline__ unsigned cvt2(float a, float b) {
  unsigned r;
  asm("v_cvt_pk_bf16_f32 %0, %1, %2" : "=v"(r) : "v"(a), "v"(b));
  return r;
}
__device__ __forceinline__ unsigned cvtr(float a, float b) {  // relu + pack
  return cvt2(fmaxf(a, 0.f), fmaxf(b, 0.f));
}
__device__ __forceinline__ float fast_rcp(float x) {
  float r;
  asm("v_rcp_f32 %0, %1" : "=v"(r) : "v"(x));
  return r;
}
__device__ __forceinline__ bf16x8 pack_b(unsigned a, unsigned b, unsigned c, unsigned d) {
  union { u32x4 u; bf16x8 v; } x;
  x.u = (u32x4){a, b, c, d};
  return x.v;
}
__device__ __forceinline__ float readlane63(float v) {
  return __int_as_float(__builtin_amdgcn_readlane(__float_as_int(v), 63));
}
// coarse z formula — single definition (bit-exact reuse everywhere)
__device__ __forceinline__ float zcoarse(float nearv, float span, int m) {
  return fmaf(span, (float)m * (1.f / 63.f), nearv);
}

// ------------- DPP wave64 primitives via update_dpp (ROW-scoped ctrls only —
// proven on gfx950 in round 7)
#define UPD(OLD, SRC, CTRL, RMASK)                                        \
  __int_as_float(__builtin_amdgcn_update_dpp(                             \
      __float_as_int(OLD), __float_as_int(SRC), CTRL, RMASK, 0xf, false))

__device__ __forceinline__ float scan_mul_dpp(float v) {
  v *= UPD(1.f, v, 0x111, 0xf);  // row_shr:1
  v *= UPD(1.f, v, 0x112, 0xf);  // row_shr:2
  v *= UPD(1.f, v, 0x114, 0xf);  // row_shr:4
  v *= UPD(1.f, v, 0x118, 0xf);  // row_shr:8
  v *= UPD(1.f, v, 0x142, 0xa);  // row_bcast:15 -> rows 1,3
  v *= UPD(1.f, v, 0x143, 0xc);  // row_bcast:31 -> rows 2,3
  return v;
}
__device__ __forceinline__ float scan_add_dpp(float v) {
  v += UPD(0.f, v, 0x111, 0xf);
  v += UPD(0.f, v, 0x112, 0xf);
  v += UPD(0.f, v, 0x114, 0xf);
  v += UPD(0.f, v, 0x118, 0xf);
  v += UPD(0.f, v, 0x142, 0xa);
  v += UPD(0.f, v, 0x143, 0xc);
  return v;
}
// Reduction: butterfly within rows, then cross-row bcast; total on lane 63.
__device__ __forceinline__ float red_add_dpp(float v) {
  v += UPD(0.f, v, 0xB1, 0xf);   // quad_perm [1,0,3,2]
  v += UPD(0.f, v, 0x4E, 0xf);   // quad_perm [2,3,0,1]
  v += UPD(0.f, v, 0x141, 0xf);  // row_half_mirror
  v += UPD(0.f, v, 0x140, 0xf);  // row_mirror
  v += UPD(0.f, v, 0x142, 0xa);  // row_bcast:15
  v += UPD(0.f, v, 0x143, 0xc);  // row_bcast:31
  return v;  // full sum valid on lane 63
}

// ---------------- weight fragment packing (64 threads — round-7 proven) -----
// pk (shorts): A1 @0 [4m][64][8] | A2 @2048 [2kt][64][8] | CA @3072 [4m][64][8]
//              C2A @5120 [2kt][64][8]
// GEMM2 A-frags use k-permutation: elem (kt,g,i) <-> nu = 32kt+16(i>>2)+4g+(i&3)
// Color GEMM1 k-map: k0=sigma(ignored,0) k1-15=geo ch1-15 (Wc1 rows 3..17),
//                    k16-18=dir (Wc1 rows 0..2), k19=bc1, k>=20: 0
__global__ void pack_weights(const float* __restrict__ Wd1, const float* __restrict__ bd1,
                             const float* __restrict__ Wd2, const float* __restrict__ Wc1,
                             const float* __restrict__ bc1, const float* __restrict__ Wc2,
                             short* __restrict__ pk) {
  const int l = threadIdx.x;  // 64 threads
  const int g = l >> 4, c = l & 15;
  // density GEMM1 A: xvec = [xh,yh,zh,th | xlo,ylo,zlo,tlo], g1 slot4 = bias
  for (int m = 0; m < 4; ++m) {
    int nu = 16 * m + c;
    short e[8] = {0, 0, 0, 0, 0, 0, 0, 0};
    if (g == 0) {
      for (int i = 0; i < 4; ++i) {
        short h = f2bf(Wd1[i * 64 + nu]);
        e[i] = h;
        e[4 + i] = h;
      }
    } else if (g == 1) {
      for (int i = 0; i < 4; ++i) {
        float w = Wd1[i * 64 + nu];
        e[i] = f2bf(w - bf2f(f2bf(w)));
      }
      e[4] = f2bf(bd1[nu]);
    }
    for (int i = 0; i < 8; ++i) pk[m * 512 + l * 8 + i] = e[i];
  }
  // density GEMM2 A (k-permuted)
  for (int kt = 0; kt < 2; ++kt)
    for (int i = 0; i < 8; ++i) {
      int nu = 32 * kt + 16 * (i >> 2) + 4 * g + (i & 3);
      pk[2048 + kt * 512 + l * 8 + i] = f2bf(Wd2[nu * 16 + c]);
    }
  // color GEMM1 A
  for (int m = 0; m < 4; ++m) {
    int nu = 16 * m + c;
    for (int i = 0; i < 8; ++i) {
      int k = 8 * g + i;
      short e = 0;
      if (k >= 1 && k <= 15) e = f2bf(Wc1[(2 + k) * 64 + nu]);
      else if (k >= 16 && k <= 18) e = f2bf(Wc1[(k - 16) * 64 + nu]);
      else if (k == 19) e = f2bf(bc1[nu]);
      pk[3072 + m * 512 + l * 8 + i] = e;
    }
  }
  // color GEMM2 A (k-permuted)
  for (int kt = 0; kt < 2; ++kt)
    for (int i = 0; i < 8; ++i) {
      int nu = 32 * kt + 16 * (i >> 2) + 4 * g + (i & 3);
      pk[5120 + kt * 512 + l * 8 + i] = (c < 3) ? f2bf(Wc2[nu * 3 + c]) : (short)0;
    }
}

// ---------------- density pass: MFMA, H entirely in registers ----------------
// Round-11 proven structure (NO GEMM1/GEMM2 interleave — that NaN'd, r12/r13).
// Writes channels 4g..4g+3 to Xc cols 4g..4g+3. Returns raw sigma.
__device__ __forceinline__ float density_pass(
    const short* __restrict__ pk, short* __restrict__ Xd, short* __restrict__ Xc,
    int lane, int g, int c, float x, float y, float z, float tf, float tLoF,
    const float* __restrict__ bd2g, int xcBase) {
  // 1. pack per-sample input [xh,yh,zh,th | xlo,ylo,zlo,tlo]
  {
    unsigned w0 = cvt2(x, y);
    unsigned w1 = cvt2(z, tf);
    union { unsigned u; float f; } ux, uy, uz;
    ux.u = w0 << 16; uy.u = w0 & 0xFFFF0000u; uz.u = w1 << 16;
    unsigned w2 = cvt2(x - ux.f, y - uy.f);
    unsigned w3 = cvt2(z - uz.f, tLoF);
    u32x4 pv; pv[0] = w0; pv[1] = w1; pv[2] = w2; pv[3] = w3;
    *(u32x4*)&Xd[lane * 8] = pv;
  }
  FENCE;

  bf16x8 A1[4];
#pragma unroll
  for (int m = 0; m < 4; ++m) A1[m] = *(const bf16x8*)(pk + m * 512 + lane * 8);

  // 2. GEMM1 (two m-halves) -> relu -> in-register B-frags P[kt][n][word]
  unsigned P[2][4][4];
#pragma unroll
  for (int mh = 0; mh < 2; ++mh) {
    f32x4 a0[4], a1[4];
#pragma unroll
    for (int n = 0; n < 4; ++n) {
      a0[n] = (f32x4){0.f, 0.f, 0.f, 0.f};
      a1[n] = (f32x4){0.f, 0.f, 0.f, 0.f};
    }
#pragma unroll
    for (int n = 0; n < 4; ++n) {
      bf16x8 v = *(const bf16x8*)&Xd[(16 * n + c) * 8];
      if (g == 1) v[4] = (short)0x3F80;  // bias slot k=12 -> 1.0
      a0[n] = __builtin_amdgcn_mfma_f32_16x16x32_bf16(A1[2 * mh], v, a0[n], 0, 0, 0);
      a1[n] = __builtin_amdgcn_mfma_f32_16x16x32_bf16(A1[2 * mh + 1], v, a1[n], 0, 0, 0);
    }
#pragma unroll
    for (int n = 0; n < 4; ++n) {
      P[mh][n][0] = cvtr(a0[n][0], a0[n][1]);
      P[mh][n][1] = cvtr(a0[n][2], a0[n][3]);
      P[mh][n][2] = cvtr(a1[n][0], a1[n][1]);
      P[mh][n][3] = cvtr(a1[n][2], a1[n][3]);
    }
  }

  // 3. GEMM2 straight from registers (k-permuted A2 matches P layout)
  bf16x8 A2[2];
  A2[0] = *(const bf16x8*)(pk + 2048 + lane * 8);
  A2[1] = *(const bf16x8*)(pk + 2048 + 512 + lane * 8);
  f32x4 o[4];
#pragma unroll
  for (int n = 0; n < 4; ++n) o[n] = (f32x4){0.f, 0.f, 0.f, 0.f};
#pragma unroll
  for (int n = 0; n < 4; ++n)
#pragma unroll
    for (int kt = 0; kt < 2; ++kt)
      o[n] = __builtin_amdgcn_mfma_f32_16x16x32_bf16(
          A2[kt], pack_b(P[kt][n][0], P[kt][n][1], P[kt][n][2], P[kt][n][3]), o[n], 0, 0, 0);

  // 4. epilogue: +bd2; channels 4g..4g+3 -> cols 4g..4g+3 (uniform, aligned)
  const float4 bd2v = *(const float4*)&bd2g[4 * g];
#pragma unroll
  for (int n = 0; n < 4; ++n) {
    o[n][0] += bd2v.x; o[n][1] += bd2v.y; o[n][2] += bd2v.z; o[n][3] += bd2v.w;
  }
#pragma unroll
  for (int n = 0; n < 4; ++n) {
    short* xr = Xc + (xcBase + 16 * n + c) * 16 + 4 * g;
    *(unsigned*)(xr + 0) = cvt2(o[n][0], o[n][1]);
    *(unsigned*)(xr + 2) = cvt2(o[n][2], o[n][3]);
  }
  FENCE;
  float t0 = __shfl(o[0][0], c);
  float t1 = __shfl(o[1][0], c);
  float t2 = __shfl(o[2][0], c);
  float t3 = __shfl(o[3][0], c);
  return (g == 0) ? t0 : (g == 1) ? t1 : (g == 2) ? t2 : t3;
}

// ---------------- main renderer: 1 ray = 1 wave = 1 block ------------------
__global__ __launch_bounds__(64, 5) void nerf_render(
    const float* __restrict__ rays_o, const float* __restrict__ rays_d,
    const float* __restrict__ time_p, const float* __restrict__ bg,
    const float* __restrict__ bd2g, const float* __restrict__ bc2g,
    const short* __restrict__ pk, float* __restrict__ out) {
  // 5120B shared. Xd (density passes) overlays zs/ss (merge onward) —
  // disjoint lifetimes, FENCE-separated.
  __shared__ __align__(64) char smem[5120];
  short* Xc  = (short*)smem;            // [0,4096)    128 rows x 32B
  short* Xd  = (short*)(smem + 4096);   // [4096,5120) 64 x 16B  (density passes)
  float* zsl = (float*)(smem + 4096);   // [4096,4608) 128 f32   (merge onward)
  float* ssl = (float*)(smem + 4608);   // [4608,5120) 128 f32

  const int lane = threadIdx.x;
  const int g = lane >> 4, c = lane & 15;
  const int ray = blockIdx.x;

  const float tf = time_p[0];
  union { unsigned u; float f; } th; th.u = cvt2(tf, tf) << 16;
  const float tLoF = tf - th.f;
  const float o0 = rays_o[ray * 3 + 0], o1 = rays_o[ray * 3 + 1], o2 = rays_o[ray * 3 + 2];
  const float d0 = rays_d[ray * 3 + 0], d1 = rays_d[ray * 3 + 1], d2 = rays_d[ray * 3 + 2];

  // ---- near / far from aabb [-1,1]^3 ----
  float nearv, farv;
  {
    float i0 = fast_rcp((fabsf(d0) < 1e-9f) ? 1e-9f : d0);
    float i1 = fast_rcp((fabsf(d1) < 1e-9f) ? 1e-9f : d1);
    float i2 = fast_rcp((fabsf(d2) < 1e-9f) ? 1e-9f : d2);
    float a0 = (-1.f - o0) * i0, b0 = (1.f - o0) * i0;
    float a1 = (-1.f - o1) * i1, b1 = (1.f - o1) * i1;
    float a2 = (-1.f - o2) * i2, b2 = (1.f - o2) * i2;
    float tmin = fmaxf(fmaxf(fminf(a0, b0), fminf(a1, b1)), fminf(a2, b2));
    float tmax = fminf(fminf(fmaxf(a0, b0), fmaxf(a1, b1)), fmaxf(a2, b2));
    nearv = fmaxf(tmin, 0.05f);
    farv = (tmax < nearv) ? (nearv + 1e-2f) : tmax;
  }
  const float span = farv - nearv;
  const float sd = span * (1.f / 64.f);

  // ---- coarse pass ----
  const float zi = zcoarse(nearv, span, lane);
  float cx = fminf(fmaxf(fmaf(d0, zi, o0), -1.f), 1.f);
  float cy = fminf(fmaxf(fmaf(d1, zi, o1), -1.f), 1.f);
  float cz = fminf(fmaxf(fmaf(d2, zi, o2), -1.f), 1.f);
  float sraw = density_pass(pk, Xd, Xc, lane, g, c, cx, cy, cz, tf, tLoF, bd2g, 0);
  const float sigma = __expf(sraw);

  // ---- coarse compositing -> cdf (registers; shfl for +-1 lane) ----
  float cdfS;
  {
    const float znext = __shfl_down(zi, 1, 64);
    const float cdelta = (lane < 63) ? (znext - zi) : sd;
    const float calpha = 1.f - __expf(-cdelta * sigma);
    float T = 1.f - calpha + 1e-15f;
    float Pincl = scan_mul_dpp(T);
    float Pexcl = __shfl_up(Pincl, 1, 64);
    if (lane == 0) Pexcl = 1.f;
    float wgt = calpha * Pexcl;
    float v = (lane >= 1 && lane <= 62) ? (wgt + 1e-5f) : 0.f;
    float S = scan_add_dpp(v);
    cdfS = S * fast_rcp(readlane63(S));  // cdf[lane]; lane0=0
  }

  // ---- inverse-CDF resampling (register shfl search, bins analytic) ----
  // range 63 -> 64 outcomes -> 6 probes suffice.
  float nzv;
  {
    const float u = ((float)lane + 0.5f) * 0.015625f;
    int lo = 0, hi = 63;
#pragma unroll
    for (int it = 0; it < 6; ++it) {  // fixed trip: uniform exec for shfl
      int mid = (lo + hi) >> 1;
      float v = __shfl(cdfS, mid, 64);
      if (lo < hi) { if (v <= u) lo = mid + 1; else hi = mid; }
    }
    int below = lo - 1;                 // lo>=1 (cdf[0]=0 <= u always)
    int above = (lo < 62) ? lo : 62;
    float c0 = __shfl(cdfS, below, 64);
    float c1 = __shfl(cdfS, above, 64);
    float b0 = 0.5f * (zcoarse(nearv, span, below) + zcoarse(nearv, span, below + 1));
    float b1 = 0.5f * (zcoarse(nearv, span, above) + zcoarse(nearv, span, above + 1));
    float dn = c1 - c0;
    dn = (dn < 1e-5f) ? 1.f : dn;
    nzv = fmaf((u - c0) * fast_rcp(dn), (b1 - b0), b0);
  }

  // ---- fine pass ----
  float fx = fminf(fmaxf(fmaf(d0, nzv, o0), -1.f), 1.f);
  float fy = fminf(fmaxf(fmaf(d1, nzv, o1), -1.f), 1.f);
  float fz = fminf(fmaxf(fmaf(d2, nzv, o2), -1.f), 1.f);
  float nsraw = density_pass(pk, Xd, Xc, lane, g, c, fx, fy, fz, tf, tLoF, bd2g, 64);
  const float nsigma = __expf(nsraw);
  FENCE;

  // ---- stable-merge ranks (range 64 -> 65 outcomes -> SEVEN probes) ----
  int r1, r2;
  {
    int lo = 0, hi = 64;
#pragma unroll
    for (int it = 0; it < 7; ++it) {  // 7 = ceil(log2(65))
      int mid = (lo + hi) >> 1;
      float v = __shfl(nzv, mid, 64);
      if (lo < hi) { if (v < zi) lo = mid + 1; else hi = mid; }
    }
    r1 = lane + lo;
  }
  {
    int lo = 0, hi = 64;
#pragma unroll
    for (int it = 0; it < 7; ++it) {
      int mid = (lo + hi) >> 1;
      if (lo < hi) { if (zcoarse(nearv, span, mid) <= nzv) lo = mid + 1; else hi = mid; }
    }
    r2 = lane + lo;
  }
  // Xd is dead from here; zs/ss overlay it.
  FENCE;
  zsl[r1] = zi;  ssl[r1] = sigma;
  zsl[r2] = nzv; ssl[r2] = nsigma;
  FENCE;

  // ---- composite over 128 sorted samples (DPP scans; weights in registers) --
  float w0, w1, wsum;
  {
    float z0 = zsl[lane];
    float z0n = zsl[lane + 1];
    float z1 = zsl[lane + 64];
    float dl0 = z0n - z0;
    float dl1 = (lane < 63) ? (zsl[lane + 65] - z1) : sd;
    float al0 = 1.f - __expf(-dl0 * ssl[lane]);
    float al1 = 1.f - __expf(-dl1 * ssl[lane + 64]);
    float T0 = 1.f - al0 + 1e-15f;
    float T1 = 1.f - al1 + 1e-15f;
    float P0 = scan_mul_dpp(T0);
    float P1 = scan_mul_dpp(T1);
    float prodLo = readlane63(P0);
    float e0 = __shfl_up(P0, 1, 64);
    float e1 = __shfl_up(P1, 1, 64);
    if (lane == 0) { e0 = 1.f; e1 = 1.f; }
    w0 = al0 * e0;
    w1 = al1 * prodLo * e1;
    wsum = red_add_dpp(w0 + w1);  // valid on lane 63
  }

  // ---- weights back in unmerged order via shfl (uniform exec) ----
  float wlo = __shfl(w0, r1 & 63, 64);
  float whi = __shfl(w1, r1 & 63, 64);
  const float wc = (r1 < 64) ? wlo : whi;
  wlo = __shfl(w0, r2 & 63, 64);
  whi = __shfl(w1, r2 & 63, 64);
  const float wf = (r2 < 64) ? wlo : whi;
  const unsigned long long mC = __ballot(wc > 1e-4f);
  const unsigned long long mF = __ballot(wf > 1e-4f);

  // ---- color MLP: H in registers; dir+bias from g==2 register operand ----
  bf16x8 CA[4];
#pragma unroll
  for (int m = 0; m < 4; ++m) CA[m] = *(const bf16x8*)(pk + 3072 + m * 512 + lane * 8);
  bf16x8 C2A[2];
  C2A[0] = *(const bf16x8*)(pk + 5120 + lane * 8);
  C2A[1] = *(const bf16x8*)(pk + 5120 + 512 + lane * 8);
  const float bc20 = bc2g[0], bc21 = bc2g[1], bc22 = bc2g[2];
  const bf16x8 bD = pack_b(cvt2(d0, d1), cvt2(d2, 1.0f), 0u, 0u);  // k16-19: d,1.0
  const bf16x8 bZ = pack_b(0u, 0u, 0u, 0u);
  const int xoffs = (g < 2) ? 8 * g : 0;

  float cr = 0.f, cgr = 0.f, cb = 0.f;
#pragma unroll
  for (int half = 0; half < 2; ++half) {
    const unsigned long long mm = half ? mF : mC;
    const float wcf = half ? wf : wc;
#pragma unroll
    for (int n = 0; n < 4; ++n) {
      if ((mm >> (16 * n)) & 0xFFFFull) {  // wave-uniform branch
        float wgt = __shfl(wcf, 16 * n + c, 64);  // uniform exec
        bf16x8 ld = *(const bf16x8*)&Xc[(64 * half + 16 * n + c) * 16 + xoffs];
        bf16x8 V = (g < 2) ? ld : ((g == 2) ? bD : bZ);
        f32x4 a[4];
#pragma unroll
        for (int m = 0; m < 4; ++m) {
          a[m] = (f32x4){0.f, 0.f, 0.f, 0.f};
          a[m] = __builtin_amdgcn_mfma_f32_16x16x32_bf16(CA[m], V, a[m], 0, 0, 0);
        }
        f32x4 oc = (f32x4){0.f, 0.f, 0.f, 0.f};
#pragma unroll
        for (int kt = 0; kt < 2; ++kt) {
          bf16x8 Bh = pack_b(cvtr(a[2 * kt][0], a[2 * kt][1]),
                             cvtr(a[2 * kt][2], a[2 * kt][3]),
                             cvtr(a[2 * kt + 1][0], a[2 * kt + 1][1]),
                             cvtr(a[2 * kt + 1][2], a[2 * kt + 1][3]));
          oc = __builtin_amdgcn_mfma_f32_16x16x32_bf16(C2A[kt], Bh, oc, 0, 0, 0);
        }
        if (g == 0 && wgt > 1e-4f) {
          cr  += wgt * fast_rcp(1.f + __expf(-(oc[0] + bc20)));
          cgr += wgt * fast_rcp(1.f + __expf(-(oc[1] + bc21)));
          cb  += wgt * fast_rcp(1.f + __expf(-(oc[2] + bc22)));
        }
      }
    }
  }

  cr = red_add_dpp(cr);
  cgr = red_add_dpp(cgr);
  cb = red_add_dpp(cb);

  if (lane == 63) {  // reductions land on lane 63
    const float rem = 1.f - wsum;
    out[ray * 3 + 0] = cr + rem * bg[0];
    out[ray * 3 + 1] = cgr + rem * bg[1];
    out[ray * 3 + 2] = cb + rem * bg[2];
  }
}

extern "C" void kernel_launch(void* const* d_in, const int* in_sizes, int n_in,
                              void* d_out, int out_size, void* d_ws, size_t ws_size,
                              hipStream_t stream) {
  const float* rays_o = (const float*)d_in[0];
  const float* rays_d = (const float*)d_in[1];
  const float* time_p = (const float*)d_in[2];
  const float* bg     = (const float*)d_in[3];
  const float* Wd1    = (const float*)d_in[4];
  const float* bd1    = (const float*)d_in[5];
  const float* Wd2    = (const float*)d_in[6];
  const float* bd2    = (const float*)d_in[7];
  const float* Wc1    = (const float*)d_in[8];
  const float* bc1    = (const float*)d_in[9];
  const float* Wc2    = (const float*)d_in[10];
  const float* bc2    = (const float*)d_in[11];

  short* pk = (short*)d_ws;  // 12 KiB packed weight fragments
  pack_weights<<<1, 64, 0, stream>>>(Wd1, bd1, Wd2, Wc1, bc1, Wc2, pk);
  nerf_render<<<NRAYS, 64, 0, stream>>>(rays_o, rays_d, time_p, bg, bd2, bc2, pk,
                                        (float*)d_out);
}

// Round 15
// 38.104 us; speedup vs baseline: 1.3913x; 1.0056x over previous
//
#include <hip/hip_runtime.h>
#include <math.h>

#define NRAYS 8192

typedef __attribute__((ext_vector_type(8))) short bf16x8;
typedef __attribute__((ext_vector_type(4))) float f32x4;
typedef __attribute__((ext_vector_type(4))) unsigned u32x4;

#define FENCE asm volatile("" ::: "memory")

__device__ __forceinline__ short f2bf(float f) {
  union { float f; unsigned u; } v; v.f = f;
  unsigned r = (v.u + 0x7FFFu + ((v.u >> 16) & 1u)) >> 16;
  return (short)r;
}
__device__ __forceinline__ float bf2f(short s) {
  union { unsigned u; float f; } v; v.u = ((unsigned)(unsigned short)s) << 16;
  return v.f;
}
// HW packed f32->bf16 (RNE): dst = {lo=bf16(a), hi=bf16(b)}
__device__ __forceinline__ unsigned cvt2(float a, float b) {
  unsigned r;
  asm("v_cvt_pk_bf16_f32 %0, %1, %2" : "=v"(r) : "v"(a), "v"(b));
  return r;
}
__device__ __forceinline__ unsigned cvtr(float a, float b) {  // relu + pack
  return cvt2(fmaxf(a, 0.f), fmaxf(b, 0.f));
}
__device__ __forceinline__ float fast_rcp(float x) {
  float r;
  asm("v_rcp_f32 %0, %1" : "=v"(r) : "v"(x));
  return r;
}
__device__ __forceinline__ bf16x8 pack_b(unsigned a, unsigned b, unsigned c, unsigned d) {
  union { u32x4 u; bf16x8 v; } x;
  x.u = (u32x4){a, b, c, d};
  return x.v;
}
__device__ __forceinline__ float readlane63(float v) {
  return __int_as_float(__builtin_amdgcn_readlane(__float_as_int(v), 63));
}
// coarse z formula — single definition (bit-exact reuse everywhere)
__device__ __forceinline__ float zcoarse(float nearv, float span, int m) {
  return fmaf(span, (float)m * (1.f / 63.f), nearv);
}

// ------------- DPP wave64 primitives via update_dpp (ROW-scoped ctrls only —
// proven on gfx950 in round 7)
#define UPD(OLD, SRC, CTRL, RMASK)                                        \
  __int_as_float(__builtin_amdgcn_update_dpp(                             \
      __float_as_int(OLD), __float_as_int(SRC), CTRL, RMASK, 0xf, false))

__device__ __forceinline__ float scan_mul_dpp(float v) {
  v *= UPD(1.f, v, 0x111, 0xf);  // row_shr:1
  v *= UPD(1.f, v, 0x112, 0xf);  // row_shr:2
  v *= UPD(1.f, v, 0x114, 0xf);  // row_shr:4
  v *= UPD(1.f, v, 0x118, 0xf);  // row_shr:8
  v *= UPD(1.f, v, 0x142, 0xa);  // row_bcast:15 -> rows 1,3
  v *= UPD(1.f, v, 0x143, 0xc);  // row_bcast:31 -> rows 2,3
  return v;
}
__device__ __forceinline__ float scan_add_dpp(float v) {
  v += UPD(0.f, v, 0x111, 0xf);
  v += UPD(0.f, v, 0x112, 0xf);
  v += UPD(0.f, v, 0x114, 0xf);
  v += UPD(0.f, v, 0x118, 0xf);
  v += UPD(0.f, v, 0x142, 0xa);
  v += UPD(0.f, v, 0x143, 0xc);
  return v;
}
// Reduction: butterfly within rows, then cross-row bcast; total on lane 63.
__device__ __forceinline__ float red_add_dpp(float v) {
  v += UPD(0.f, v, 0xB1, 0xf);   // quad_perm [1,0,3,2]
  v += UPD(0.f, v, 0x4E, 0xf);   // quad_perm [2,3,0,1]
  v += UPD(0.f, v, 0x141, 0xf);  // row_half_mirror
  v += UPD(0.f, v, 0x140, 0xf);  // row_mirror
  v += UPD(0.f, v, 0x142, 0xa);  // row_bcast:15
  v += UPD(0.f, v, 0x143, 0xc);  // row_bcast:31
  return v;  // full sum valid on lane 63
}

// ---------------- weight fragment packing (64 threads — round-7 proven) -----
// pk (shorts): A1 @0 [4m][64][8] | A2 @2048 [2kt][64][8] | CA @3072 [4m][64][8]
//              C2A @5120 [2kt][64][8]
// GEMM2 A-frags use k-permutation: elem (kt,g,i) <-> nu = 32kt+16(i>>2)+4g+(i&3)
// Color GEMM1 k-map: k0=sigma(ignored,0) k1-15=geo ch1-15 (Wc1 rows 3..17),
//                    k16-18=dir (Wc1 rows 0..2), k19=bc1, k>=20: 0
__global__ void pack_weights(const float* __restrict__ Wd1, const float* __restrict__ bd1,
                             const float* __restrict__ Wd2, const float* __restrict__ Wc1,
                             const float* __restrict__ bc1, const float* __restrict__ Wc2,
                             short* __restrict__ pk) {
  const int l = threadIdx.x;  // 64 threads
  const int g = l >> 4, c = l & 15;
  // density GEMM1 A: xvec = [xh,yh,zh,th | xlo,ylo,zlo,tlo], g1 slot4 = bias
  for (int m = 0; m < 4; ++m) {
    int nu = 16 * m + c;
    short e[8] = {0, 0, 0, 0, 0, 0, 0, 0};
    if (g == 0) {
      for (int i = 0; i < 4; ++i) {
        short h = f2bf(Wd1[i * 64 + nu]);
        e[i] = h;
        e[4 + i] = h;
      }
    } else if (g == 1) {
      for (int i = 0; i < 4; ++i) {
        float w = Wd1[i * 64 + nu];
        e[i] = f2bf(w - bf2f(f2bf(w)));
      }
      e[4] = f2bf(bd1[nu]);
    }
    for (int i = 0; i < 8; ++i) pk[m * 512 + l * 8 + i] = e[i];
  }
  // density GEMM2 A (k-permuted)
  for (int kt = 0; kt < 2; ++kt)
    for (int i = 0; i < 8; ++i) {
      int nu = 32 * kt + 16 * (i >> 2) + 4 * g + (i & 3);
      pk[2048 + kt * 512 + l * 8 + i] = f2bf(Wd2[nu * 16 + c]);
    }
  // color GEMM1 A
  for (int m = 0; m < 4; ++m) {
    int nu = 16 * m + c;
    for (int i = 0; i < 8; ++i) {
      int k = 8 * g + i;
      short e = 0;
      if (k >= 1 && k <= 15) e = f2bf(Wc1[(2 + k) * 64 + nu]);
      else if (k >= 16 && k <= 18) e = f2bf(Wc1[(k - 16) * 64 + nu]);
      else if (k == 19) e = f2bf(bc1[nu]);
      pk[3072 + m * 512 + l * 8 + i] = e;
    }
  }
  // color GEMM2 A (k-permuted)
  for (int kt = 0; kt < 2; ++kt)
    for (int i = 0; i < 8; ++i) {
      int nu = 32 * kt + 16 * (i >> 2) + 4 * g + (i & 3);
      pk[5120 + kt * 512 + l * 8 + i] = (c < 3) ? f2bf(Wc2[nu * 3 + c]) : (short)0;
    }
}

// ---------------- density pass: MFMA, H entirely in registers ----------------
// Round-11 proven structure (NO GEMM1/GEMM2 interleave — that NaN'd, r12/r13).
// Writes channels 4g..4g+3 to Xc cols 4g..4g+3. Returns raw sigma.
__device__ __forceinline__ float density_pass(
    const short* __restrict__ pk, short* __restrict__ Xd, short* __restrict__ Xc,
    int lane, int g, int c, float x, float y, float z, float tf, float tLoF,
    const float* __restrict__ bd2g, int xcBase) {
  // 1. pack per-sample input [xh,yh,zh,th | xlo,ylo,zlo,tlo]
  {
    unsigned w0 = cvt2(x, y);
    unsigned w1 = cvt2(z, tf);
    union { unsigned u; float f; } ux, uy, uz;
    ux.u = w0 << 16; uy.u = w0 & 0xFFFF0000u; uz.u = w1 << 16;
    unsigned w2 = cvt2(x - ux.f, y - uy.f);
    unsigned w3 = cvt2(z - uz.f, tLoF);
    u32x4 pv; pv[0] = w0; pv[1] = w1; pv[2] = w2; pv[3] = w3;
    *(u32x4*)&Xd[lane * 8] = pv;
  }
  FENCE;

  bf16x8 A1[4];
#pragma unroll
  for (int m = 0; m < 4; ++m) A1[m] = *(const bf16x8*)(pk + m * 512 + lane * 8);

  __builtin_amdgcn_s_setprio(1);
  // 2. GEMM1 (two m-halves) -> relu -> in-register B-frags P[kt][n][word]
  unsigned P[2][4][4];
#pragma unroll
  for (int mh = 0; mh < 2; ++mh) {
    f32x4 a0[4], a1[4];
#pragma unroll
    for (int n = 0; n < 4; ++n) {
      a0[n] = (f32x4){0.f, 0.f, 0.f, 0.f};
      a1[n] = (f32x4){0.f, 0.f, 0.f, 0.f};
    }
#pragma unroll
    for (int n = 0; n < 4; ++n) {
      bf16x8 v = *(const bf16x8*)&Xd[(16 * n + c) * 8];
      if (g == 1) v[4] = (short)0x3F80;  // bias slot k=12 -> 1.0
      a0[n] = __builtin_amdgcn_mfma_f32_16x16x32_bf16(A1[2 * mh], v, a0[n], 0, 0, 0);
      a1[n] = __builtin_amdgcn_mfma_f32_16x16x32_bf16(A1[2 * mh + 1], v, a1[n], 0, 0, 0);
    }
#pragma unroll
    for (int n = 0; n < 4; ++n) {
      P[mh][n][0] = cvtr(a0[n][0], a0[n][1]);
      P[mh][n][1] = cvtr(a0[n][2], a0[n][3]);
      P[mh][n][2] = cvtr(a1[n][0], a1[n][1]);
      P[mh][n][3] = cvtr(a1[n][2], a1[n][3]);
    }
  }

  // 3. GEMM2 straight from registers (k-permuted A2 matches P layout)
  bf16x8 A2[2];
  A2[0] = *(const bf16x8*)(pk + 2048 + lane * 8);
  A2[1] = *(const bf16x8*)(pk + 2048 + 512 + lane * 8);
  f32x4 o[4];
#pragma unroll
  for (int n = 0; n < 4; ++n) o[n] = (f32x4){0.f, 0.f, 0.f, 0.f};
#pragma unroll
  for (int n = 0; n < 4; ++n)
#pragma unroll
    for (int kt = 0; kt < 2; ++kt)
      o[n] = __builtin_amdgcn_mfma_f32_16x16x32_bf16(
          A2[kt], pack_b(P[kt][n][0], P[kt][n][1], P[kt][n][2], P[kt][n][3]), o[n], 0, 0, 0);
  __builtin_amdgcn_s_setprio(0);

  // 4. epilogue: +bd2; channels 4g..4g+3 -> cols 4g..4g+3 (uniform, aligned)
  const float4 bd2v = *(const float4*)&bd2g[4 * g];
#pragma unroll
  for (int n = 0; n < 4; ++n) {
    o[n][0] += bd2v.x; o[n][1] += bd2v.y; o[n][2] += bd2v.z; o[n][3] += bd2v.w;
  }
#pragma unroll
  for (int n = 0; n < 4; ++n) {
    short* xr = Xc + (xcBase + 16 * n + c) * 16 + 4 * g;
    *(unsigned*)(xr + 0) = cvt2(o[n][0], o[n][1]);
    *(unsigned*)(xr + 2) = cvt2(o[n][2], o[n][3]);
  }
  FENCE;
  float t0 = __shfl(o[0][0], c);
  float t1 = __shfl(o[1][0], c);
  float t2 = __shfl(o[2][0], c);
  float t3 = __shfl(o[3][0], c);
  return (g == 0) ? t0 : (g == 1) ? t1 : (g == 2) ? t2 : t3;
}

// ---------------- main renderer: 1 ray = 1 wave = 1 block ------------------
__global__ __launch_bounds__(64, 5) void nerf_render(
    const float* __restrict__ rays_o, const float* __restrict__ rays_d,
    const float* __restrict__ time_p, const float* __restrict__ bg,
    const float* __restrict__ bd2g, const float* __restrict__ bc2g,
    const short* __restrict__ pk, float* __restrict__ out) {
  // 5120B shared. Xd (density passes) overlays zs/ss (merge onward) —
  // disjoint lifetimes, FENCE-separated.
  __shared__ __align__(64) char smem[5120];
  short* Xc  = (short*)smem;            // [0,4096)    128 rows x 32B
  short* Xd  = (short*)(smem + 4096);   // [4096,5120) 64 x 16B  (density passes)
  float* zsl = (float*)(smem + 4096);   // [4096,4608) 128 f32   (merge onward)
  float* ssl = (float*)(smem + 4608);   // [4608,5120) 128 f32

  const int lane = threadIdx.x;
  const int g = lane >> 4, c = lane & 15;
  const int ray = blockIdx.x;

  const float tf = time_p[0];
  union { unsigned u; float f; } th; th.u = cvt2(tf, tf) << 16;
  const float tLoF = tf - th.f;
  const float o0 = rays_o[ray * 3 + 0], o1 = rays_o[ray * 3 + 1], o2 = rays_o[ray * 3 + 2];
  const float d0 = rays_d[ray * 3 + 0], d1 = rays_d[ray * 3 + 1], d2 = rays_d[ray * 3 + 2];

  // ---- near / far from aabb [-1,1]^3 ----
  float nearv, farv;
  {
    float i0 = fast_rcp((fabsf(d0) < 1e-9f) ? 1e-9f : d0);
    float i1 = fast_rcp((fabsf(d1) < 1e-9f) ? 1e-9f : d1);
    float i2 = fast_rcp((fabsf(d2) < 1e-9f) ? 1e-9f : d2);
    float a0 = (-1.f - o0) * i0, b0 = (1.f - o0) * i0;
    float a1 = (-1.f - o1) * i1, b1 = (1.f - o1) * i1;
    float a2 = (-1.f - o2) * i2, b2 = (1.f - o2) * i2;
    float tmin = fmaxf(fmaxf(fminf(a0, b0), fminf(a1, b1)), fminf(a2, b2));
    float tmax = fminf(fminf(fmaxf(a0, b0), fmaxf(a1, b1)), fmaxf(a2, b2));
    nearv = fmaxf(tmin, 0.05f);
    farv = (tmax < nearv) ? (nearv + 1e-2f) : tmax;
  }
  const float span = farv - nearv;
  const float sd = span * (1.f / 64.f);

  // ---- coarse pass ----
  const float zi = zcoarse(nearv, span, lane);
  float cx = fminf(fmaxf(fmaf(d0, zi, o0), -1.f), 1.f);
  float cy = fminf(fmaxf(fmaf(d1, zi, o1), -1.f), 1.f);
  float cz = fminf(fmaxf(fmaf(d2, zi, o2), -1.f), 1.f);
  float sraw = density_pass(pk, Xd, Xc, lane, g, c, cx, cy, cz, tf, tLoF, bd2g, 0);
  const float sigma = __expf(sraw);

  // ---- coarse compositing -> cdf (registers; shfl for +-1 lane) ----
  float cdfS;
  {
    const float znext = __shfl_down(zi, 1, 64);
    const float cdelta = (lane < 63) ? (znext - zi) : sd;
    const float calpha = 1.f - __expf(-cdelta * sigma);
    float T = 1.f - calpha + 1e-15f;
    float Pincl = scan_mul_dpp(T);
    float Pexcl = __shfl_up(Pincl, 1, 64);
    if (lane == 0) Pexcl = 1.f;
    float wgt = calpha * Pexcl;
    float v = (lane >= 1 && lane <= 62) ? (wgt + 1e-5f) : 0.f;
    float S = scan_add_dpp(v);
    cdfS = S * fast_rcp(readlane63(S));  // cdf[lane]; lane0=0
  }

  // ---- inverse-CDF resampling (register shfl search, bins analytic) ----
  // range 63 -> 64 outcomes -> 6 probes suffice.
  float nzv;
  {
    const float u = ((float)lane + 0.5f) * 0.015625f;
    int lo = 0, hi = 63;
#pragma unroll
    for (int it = 0; it < 6; ++it) {  // fixed trip: uniform exec for shfl
      int mid = (lo + hi) >> 1;
      float v = __shfl(cdfS, mid, 64);
      if (lo < hi) { if (v <= u) lo = mid + 1; else hi = mid; }
    }
    int below = lo - 1;                 // lo>=1 (cdf[0]=0 <= u always)
    int above = (lo < 62) ? lo : 62;
    float c0 = __shfl(cdfS, below, 64);
    float c1 = __shfl(cdfS, above, 64);
    float b0 = 0.5f * (zcoarse(nearv, span, below) + zcoarse(nearv, span, below + 1));
    float b1 = 0.5f * (zcoarse(nearv, span, above) + zcoarse(nearv, span, above + 1));
    float dn = c1 - c0;
    dn = (dn < 1e-5f) ? 1.f : dn;
    nzv = fmaf((u - c0) * fast_rcp(dn), (b1 - b0), b0);
  }

  // ---- fine pass ----
  float fx = fminf(fmaxf(fmaf(d0, nzv, o0), -1.f), 1.f);
  float fy = fminf(fmaxf(fmaf(d1, nzv, o1), -1.f), 1.f);
  float fz = fminf(fmaxf(fmaf(d2, nzv, o2), -1.f), 1.f);
  float nsraw = density_pass(pk, Xd, Xc, lane, g, c, fx, fy, fz, tf, tLoF, bd2g, 64);
  const float nsigma = __expf(nsraw);
  FENCE;

  // ---- stable-merge ranks ----
  // r1: shfl binary search over fine z (data-dependent; 65 outcomes -> 7 probes)
  int r1, r2;
  {
    int lo = 0, hi = 64;
#pragma unroll
    for (int it = 0; it < 7; ++it) {  // 7 = ceil(log2(65))
      int mid = (lo + hi) >> 1;
      float v = __shfl(nzv, mid, 64);
      if (lo < hi) { if (v < zi) lo = mid + 1; else hi = mid; }
    }
    r1 = lane + lo;
  }
  // r2: coarse grid is ANALYTIC -> arithmetic estimate + exact-predicate
  // verification (+-2 covers estimate error; predicate monotone in m).
  // Provably identical result to the binary search over zcoarse.
  {
    float t = (nzv - nearv) * fast_rcp(span) * 63.f;
    int lo = (int)fminf(fmaxf(t, 0.f), 64.f);
    if (lo < 64 && zcoarse(nearv, span, lo) <= nzv) ++lo;
    if (lo < 64 && zcoarse(nearv, span, lo) <= nzv) ++lo;
    if (lo > 0 && zcoarse(nearv, span, lo - 1) > nzv) --lo;
    if (lo > 0 && zcoarse(nearv, span, lo - 1) > nzv) --lo;
    r2 = lane + lo;
  }
  // Xd is dead from here; zs/ss overlay it.
  FENCE;
  zsl[r1] = zi;  ssl[r1] = sigma;
  zsl[r2] = nzv; ssl[r2] = nsigma;
  FENCE;

  // ---- composite over 128 sorted samples (DPP scans; weights in registers) --
  float w0, w1, wsum;
  {
    float z0 = zsl[lane];
    float z0n = zsl[lane + 1];
    float z1 = zsl[lane + 64];
    float dl0 = z0n - z0;
    float dl1 = (lane < 63) ? (zsl[lane + 65] - z1) : sd;
    float al0 = 1.f - __expf(-dl0 * ssl[lane]);
    float al1 = 1.f - __expf(-dl1 * ssl[lane + 64]);
    float T0 = 1.f - al0 + 1e-15f;
    float T1 = 1.f - al1 + 1e-15f;
    float P0 = scan_mul_dpp(T0);
    float P1 = scan_mul_dpp(T1);
    float prodLo = readlane63(P0);
    float e0 = __shfl_up(P0, 1, 64);
    float e1 = __shfl_up(P1, 1, 64);
    if (lane == 0) { e0 = 1.f; e1 = 1.f; }
    w0 = al0 * e0;
    w1 = al1 * prodLo * e1;
    wsum = red_add_dpp(w0 + w1);  // valid on lane 63
  }

  // ---- weights back in unmerged order via shfl (uniform exec) ----
  float wlo = __shfl(w0, r1 & 63, 64);
  float whi = __shfl(w1, r1 & 63, 64);
  const float wc = (r1 < 64) ? wlo : whi;
  wlo = __shfl(w0, r2 & 63, 64);
  whi = __shfl(w1, r2 & 63, 64);
  const float wf = (r2 < 64) ? wlo : whi;
  const unsigned long long mC = __ballot(wc > 1e-4f);
  const unsigned long long mF = __ballot(wf > 1e-4f);

  // ---- color MLP: H in registers; dir+bias from g==2 register operand ----
  bf16x8 CA[4];
#pragma unroll
  for (int m = 0; m < 4; ++m) CA[m] = *(const bf16x8*)(pk + 3072 + m * 512 + lane * 8);
  bf16x8 C2A[2];
  C2A[0] = *(const bf16x8*)(pk + 5120 + lane * 8);
  C2A[1] = *(const bf16x8*)(pk + 5120 + 512 + lane * 8);
  const float bc20 = bc2g[0], bc21 = bc2g[1], bc22 = bc2g[2];
  const bf16x8 bD = pack_b(cvt2(d0, d1), cvt2(d2, 1.0f), 0u, 0u);  // k16-19: d,1.0
  const bf16x8 bZ = pack_b(0u, 0u, 0u, 0u);
  const int xoffs = (g < 2) ? 8 * g : 0;

  float cr = 0.f, cgr = 0.f, cb = 0.f;
#pragma unroll
  for (int half = 0; half < 2; ++half) {
    const unsigned long long mm = half ? mF : mC;
    const float wcf = half ? wf : wc;
#pragma unroll
    for (int n = 0; n < 4; ++n) {
      if ((mm >> (16 * n)) & 0xFFFFull) {  // wave-uniform branch
        float wgt = __shfl(wcf, 16 * n + c, 64);  // uniform exec
        bf16x8 ld = *(const bf16x8*)&Xc[(64 * half + 16 * n + c) * 16 + xoffs];
        bf16x8 V = (g < 2) ? ld : ((g == 2) ? bD : bZ);
        __builtin_amdgcn_s_setprio(1);
        f32x4 a[4];
#pragma unroll
        for (int m = 0; m < 4; ++m) {
          a[m] = (f32x4){0.f, 0.f, 0.f, 0.f};
          a[m] = __builtin_amdgcn_mfma_f32_16x16x32_bf16(CA[m], V, a[m], 0, 0, 0);
        }
        f32x4 oc = (f32x4){0.f, 0.f, 0.f, 0.f};
#pragma unroll
        for (int kt = 0; kt < 2; ++kt) {
          bf16x8 Bh = pack_b(cvtr(a[2 * kt][0], a[2 * kt][1]),
                             cvtr(a[2 * kt][2], a[2 * kt][3]),
                             cvtr(a[2 * kt + 1][0], a[2 * kt + 1][1]),
                             cvtr(a[2 * kt + 1][2], a[2 * kt + 1][3]));
          oc = __builtin_amdgcn_mfma_f32_16x16x32_bf16(C2A[kt], Bh, oc, 0, 0, 0);
        }
        __builtin_amdgcn_s_setprio(0);
        if (g == 0 && wgt > 1e-4f) {
          cr  += wgt * fast_rcp(1.f + __expf(-(oc[0] + bc20)));
          cgr += wgt * fast_rcp(1.f + __expf(-(oc[1] + bc21)));
          cb  += wgt * fast_rcp(1.f + __expf(-(oc[2] + bc22)));
        }
      }
    }
  }

  cr = red_add_dpp(cr);
  cgr = red_add_dpp(cgr);
  cb = red_add_dpp(cb);

  if (lane == 63) {  // reductions land on lane 63
    const float rem = 1.f - wsum;
    out[ray * 3 + 0] = cr + rem * bg[0];
    out[ray * 3 + 1] = cgr + rem * bg[1];
    out[ray * 3 + 2] = cb + rem * bg[2];
  }
}

extern "C" void kernel_launch(void* const* d_in, const int* in_sizes, int n_in,
                              void* d_out, int out_size, void* d_ws, size_t ws_size,
                              hipStream_t stream) {
  const float* rays_o = (const float*)d_in[0];
  const float* rays_d = (const float*)d_in[1];
  const float* time_p = (const float*)d_in[2];
  const float* bg     = (const float*)d_in[3];
  const float* Wd1    = (const float*)d_in[4];
  const float* bd1    = (const float*)d_in[5];
  const float* Wd2    = (const float*)d_in[6];
  const float* bd2    = (const float*)d_in[7];
  const float* Wc1    = (const float*)d_in[8];
  const float* bc1    = (const float*)d_in[9];
  const float* Wc2    = (const float*)d_in[10];
  const float* bc2    = (const float*)d_in[11];

  short* pk = (short*)d_ws;  // 12 KiB packed weight fragments
  pack_weights<<<1, 64, 0, stream>>>(Wd1, bd1, Wd2, Wc1, bc1, Wc2, pk);
  nerf_render<<<NRAYS, 64, 0, stream>>>(rays_o, rays_d, time_p, bg, bd2, bc2, pk,
                                        (float*)d_out);
}

// Round 16
// 37.893 us; speedup vs baseline: 1.3991x; 1.0056x over previous
//
#include <hip/hip_runtime.h>
#include <math.h>

#define NRAYS 8192

typedef __attribute__((ext_vector_type(8))) short bf16x8;
typedef __attribute__((ext_vector_type(4))) float f32x4;
typedef __attribute__((ext_vector_type(4))) unsigned u32x4;

#define FENCE asm volatile("" ::: "memory")

__device__ __forceinline__ short f2bf(float f) {
  union { float f; unsigned u; } v; v.f = f;
  unsigned r = (v.u + 0x7FFFu + ((v.u >> 16) & 1u)) >> 16;
  return (short)r;
}
__device__ __forceinline__ float bf2f(short s) {
  union { unsigned u; float f; } v; v.u = ((unsigned)(unsigned short)s) << 16;
  return v.f;
}
// HW packed f32->bf16 (RNE): dst = {lo=bf16(a), hi=bf16(b)}
__device__ __forceinline__ unsigned cvt2(float a, float b) {
  unsigned r;
  asm("v_cvt_pk_bf16_f32 %0, %1, %2" : "=v"(r) : "v"(a), "v"(b));
  return r;
}
__device__ __forceinline__ unsigned cvtr(float a, float b) {  // relu + pack
  return cvt2(fmaxf(a, 0.f), fmaxf(b, 0.f));
}
__device__ __forceinline__ float fast_rcp(float x) {
  float r;
  asm("v_rcp_f32 %0, %1" : "=v"(r) : "v"(x));
  return r;
}
__device__ __forceinline__ bf16x8 pack_b(unsigned a, unsigned b, unsigned c, unsigned d) {
  union { u32x4 u; bf16x8 v; } x;
  x.u = (u32x4){a, b, c, d};
  return x.v;
}
__device__ __forceinline__ float readlane63(float v) {
  return __int_as_float(__builtin_amdgcn_readlane(__float_as_int(v), 63));
}
// coarse z formula — single definition (bit-exact reuse everywhere)
__device__ __forceinline__ float zcoarse(float nearv, float span, int m) {
  return fmaf(span, (float)m * (1.f / 63.f), nearv);
}

// ------------- DPP wave64 primitives via update_dpp (ROW-scoped ctrls only —
// proven on gfx950 in round 7)
#define UPD(OLD, SRC, CTRL, RMASK)                                        \
  __int_as_float(__builtin_amdgcn_update_dpp(                             \
      __float_as_int(OLD), __float_as_int(SRC), CTRL, RMASK, 0xf, false))

__device__ __forceinline__ float scan_mul_dpp(float v) {
  v *= UPD(1.f, v, 0x111, 0xf);  // row_shr:1
  v *= UPD(1.f, v, 0x112, 0xf);  // row_shr:2
  v *= UPD(1.f, v, 0x114, 0xf);  // row_shr:4
  v *= UPD(1.f, v, 0x118, 0xf);  // row_shr:8
  v *= UPD(1.f, v, 0x142, 0xa);  // row_bcast:15 -> rows 1,3
  v *= UPD(1.f, v, 0x143, 0xc);  // row_bcast:31 -> rows 2,3
  return v;
}
__device__ __forceinline__ float scan_add_dpp(float v) {
  v += UPD(0.f, v, 0x111, 0xf);
  v += UPD(0.f, v, 0x112, 0xf);
  v += UPD(0.f, v, 0x114, 0xf);
  v += UPD(0.f, v, 0x118, 0xf);
  v += UPD(0.f, v, 0x142, 0xa);
  v += UPD(0.f, v, 0x143, 0xc);
  return v;
}
// Reduction: butterfly within rows, then cross-row bcast; total on lane 63.
__device__ __forceinline__ float red_add_dpp(float v) {
  v += UPD(0.f, v, 0xB1, 0xf);   // quad_perm [1,0,3,2]
  v += UPD(0.f, v, 0x4E, 0xf);   // quad_perm [2,3,0,1]
  v += UPD(0.f, v, 0x141, 0xf);  // row_half_mirror
  v += UPD(0.f, v, 0x140, 0xf);  // row_mirror
  v += UPD(0.f, v, 0x142, 0xa);  // row_bcast:15
  v += UPD(0.f, v, 0x143, 0xc);  // row_bcast:31
  return v;  // full sum valid on lane 63
}

// ---------------- weight fragment packing (64 threads — round-7 proven) -----
// pk (shorts): A1 @0 [4m][64][8] | A2 @2048 [2kt][64][8] | CA @3072 [4m][64][8]
//              C2A @5120 [2kt][64][8]
// GEMM2 A-frags use k-permutation: elem (kt,g,i) <-> nu = 32kt+16(i>>2)+4g+(i&3)
// Color GEMM1 k-map: k0=sigma(ignored,0) k1-15=geo ch1-15 (Wc1 rows 3..17),
//                    k16-18=dir (Wc1 rows 0..2), k19=bc1, k>=20: 0
__global__ void pack_weights(const float* __restrict__ Wd1, const float* __restrict__ bd1,
                             const float* __restrict__ Wd2, const float* __restrict__ Wc1,
                             const float* __restrict__ bc1, const float* __restrict__ Wc2,
                             short* __restrict__ pk) {
  const int l = threadIdx.x;  // 64 threads
  const int g = l >> 4, c = l & 15;
  // density GEMM1 A: xvec = [xh,yh,zh,th | xlo,ylo,zlo,tlo], g1 slot4 = bias
  for (int m = 0; m < 4; ++m) {
    int nu = 16 * m + c;
    short e[8] = {0, 0, 0, 0, 0, 0, 0, 0};
    if (g == 0) {
      for (int i = 0; i < 4; ++i) {
        short h = f2bf(Wd1[i * 64 + nu]);
        e[i] = h;
        e[4 + i] = h;
      }
    } else if (g == 1) {
      for (int i = 0; i < 4; ++i) {
        float w = Wd1[i * 64 + nu];
        e[i] = f2bf(w - bf2f(f2bf(w)));
      }
      e[4] = f2bf(bd1[nu]);
    }
    for (int i = 0; i < 8; ++i) pk[m * 512 + l * 8 + i] = e[i];
  }
  // density GEMM2 A (k-permuted)
  for (int kt = 0; kt < 2; ++kt)
    for (int i = 0; i < 8; ++i) {
      int nu = 32 * kt + 16 * (i >> 2) + 4 * g + (i & 3);
      pk[2048 + kt * 512 + l * 8 + i] = f2bf(Wd2[nu * 16 + c]);
    }
  // color GEMM1 A
  for (int m = 0; m < 4; ++m) {
    int nu = 16 * m + c;
    for (int i = 0; i < 8; ++i) {
      int k = 8 * g + i;
      short e = 0;
      if (k >= 1 && k <= 15) e = f2bf(Wc1[(2 + k) * 64 + nu]);
      else if (k >= 16 && k <= 18) e = f2bf(Wc1[(k - 16) * 64 + nu]);
      else if (k == 19) e = f2bf(bc1[nu]);
      pk[3072 + m * 512 + l * 8 + i] = e;
    }
  }
  // color GEMM2 A (k-permuted)
  for (int kt = 0; kt < 2; ++kt)
    for (int i = 0; i < 8; ++i) {
      int nu = 32 * kt + 16 * (i >> 2) + 4 * g + (i & 3);
      pk[5120 + kt * 512 + l * 8 + i] = (c < 3) ? f2bf(Wc2[nu * 3 + c]) : (short)0;
    }
}

// ---------------- density pass: MFMA, H entirely in registers ----------------
// Round-11 proven structure (NO GEMM1/GEMM2 interleave — that NaN'd, r12/r13).
// Writes channels 4g..4g+3 to Xc cols 4g..4g+3. Returns raw sigma.
__device__ __forceinline__ float density_pass(
    const short* __restrict__ pk, short* __restrict__ Xd, short* __restrict__ Xc,
    int lane, int g, int c, float x, float y, float z, float tf, float tLoF,
    const float* __restrict__ bd2g, int xcBase) {
  // 1. pack per-sample input [xh,yh,zh,th | xlo,ylo,zlo,tlo]
  {
    unsigned w0 = cvt2(x, y);
    unsigned w1 = cvt2(z, tf);
    union { unsigned u; float f; } ux, uy, uz;
    ux.u = w0 << 16; uy.u = w0 & 0xFFFF0000u; uz.u = w1 << 16;
    unsigned w2 = cvt2(x - ux.f, y - uy.f);
    unsigned w3 = cvt2(z - uz.f, tLoF);
    u32x4 pv; pv[0] = w0; pv[1] = w1; pv[2] = w2; pv[3] = w3;
    *(u32x4*)&Xd[lane * 8] = pv;
  }
  FENCE;

  bf16x8 A1[4];
#pragma unroll
  for (int m = 0; m < 4; ++m) A1[m] = *(const bf16x8*)(pk + m * 512 + lane * 8);

  __builtin_amdgcn_s_setprio(1);
  // 2. GEMM1 (two m-halves) -> relu -> in-register B-frags P[kt][n][word]
  unsigned P[2][4][4];
#pragma unroll
  for (int mh = 0; mh < 2; ++mh) {
    f32x4 a0[4], a1[4];
#pragma unroll
    for (int n = 0; n < 4; ++n) {
      a0[n] = (f32x4){0.f, 0.f, 0.f, 0.f};
      a1[n] = (f32x4){0.f, 0.f, 0.f, 0.f};
    }
#pragma unroll
    for (int n = 0; n < 4; ++n) {
      bf16x8 v = *(const bf16x8*)&Xd[(16 * n + c) * 8];
      if (g == 1) v[4] = (short)0x3F80;  // bias slot k=12 -> 1.0
      a0[n] = __builtin_amdgcn_mfma_f32_16x16x32_bf16(A1[2 * mh], v, a0[n], 0, 0, 0);
      a1[n] = __builtin_amdgcn_mfma_f32_16x16x32_bf16(A1[2 * mh + 1], v, a1[n], 0, 0, 0);
    }
#pragma unroll
    for (int n = 0; n < 4; ++n) {
      P[mh][n][0] = cvtr(a0[n][0], a0[n][1]);
      P[mh][n][1] = cvtr(a0[n][2], a0[n][3]);
      P[mh][n][2] = cvtr(a1[n][0], a1[n][1]);
      P[mh][n][3] = cvtr(a1[n][2], a1[n][3]);
    }
  }

  // 3. GEMM2 straight from registers (k-permuted A2 matches P layout)
  bf16x8 A2[2];
  A2[0] = *(const bf16x8*)(pk + 2048 + lane * 8);
  A2[1] = *(const bf16x8*)(pk + 2048 + 512 + lane * 8);
  f32x4 o[4];
#pragma unroll
  for (int n = 0; n < 4; ++n) o[n] = (f32x4){0.f, 0.f, 0.f, 0.f};
#pragma unroll
  for (int n = 0; n < 4; ++n)
#pragma unroll
    for (int kt = 0; kt < 2; ++kt)
      o[n] = __builtin_amdgcn_mfma_f32_16x16x32_bf16(
          A2[kt], pack_b(P[kt][n][0], P[kt][n][1], P[kt][n][2], P[kt][n][3]), o[n], 0, 0, 0);
  __builtin_amdgcn_s_setprio(0);

  // 4. epilogue: +bd2; channels 4g..4g+3 -> cols 4g..4g+3 (uniform, aligned)
  const float4 bd2v = *(const float4*)&bd2g[4 * g];
#pragma unroll
  for (int n = 0; n < 4; ++n) {
    o[n][0] += bd2v.x; o[n][1] += bd2v.y; o[n][2] += bd2v.z; o[n][3] += bd2v.w;
  }
#pragma unroll
  for (int n = 0; n < 4; ++n) {
    short* xr = Xc + (xcBase + 16 * n + c) * 16 + 4 * g;
    *(unsigned*)(xr + 0) = cvt2(o[n][0], o[n][1]);
    *(unsigned*)(xr + 2) = cvt2(o[n][2], o[n][3]);
  }
  FENCE;
  float t0 = __shfl(o[0][0], c);
  float t1 = __shfl(o[1][0], c);
  float t2 = __shfl(o[2][0], c);
  float t3 = __shfl(o[3][0], c);
  return (g == 0) ? t0 : (g == 1) ? t1 : (g == 2) ? t2 : t3;
}

// ---------------- main renderer: 1 ray = 1 wave = 1 block ------------------
__global__ __launch_bounds__(64, 5) void nerf_render(
    const float* __restrict__ rays_o, const float* __restrict__ rays_d,
    const float* __restrict__ time_p, const float* __restrict__ bg,
    const float* __restrict__ bd2g, const float* __restrict__ bc2g,
    const short* __restrict__ pk, float* __restrict__ out) {
  // 5120B shared. Xd (density passes) overlays zs/ss (merge onward) —
  // disjoint lifetimes, FENCE-separated.
  __shared__ __align__(64) char smem[5120];
  short* Xc  = (short*)smem;            // [0,4096)    128 rows x 32B
  short* Xd  = (short*)(smem + 4096);   // [4096,5120) 64 x 16B  (density passes)
  float* zsl = (float*)(smem + 4096);   // [4096,4608) 128 f32   (merge onward)
  float* ssl = (float*)(smem + 4608);   // [4608,5120) 128 f32

  const int lane = threadIdx.x;
  const int g = lane >> 4, c = lane & 15;
  const int ray = blockIdx.x;

  const float tf = time_p[0];
  union { unsigned u; float f; } th; th.u = cvt2(tf, tf) << 16;
  const float tLoF = tf - th.f;
  const float o0 = rays_o[ray * 3 + 0], o1 = rays_o[ray * 3 + 1], o2 = rays_o[ray * 3 + 2];
  const float d0 = rays_d[ray * 3 + 0], d1 = rays_d[ray * 3 + 1], d2 = rays_d[ray * 3 + 2];

  // ---- near / far from aabb [-1,1]^3 ----
  float nearv, farv;
  {
    float i0 = fast_rcp((fabsf(d0) < 1e-9f) ? 1e-9f : d0);
    float i1 = fast_rcp((fabsf(d1) < 1e-9f) ? 1e-9f : d1);
    float i2 = fast_rcp((fabsf(d2) < 1e-9f) ? 1e-9f : d2);
    float a0 = (-1.f - o0) * i0, b0 = (1.f - o0) * i0;
    float a1 = (-1.f - o1) * i1, b1 = (1.f - o1) * i1;
    float a2 = (-1.f - o2) * i2, b2 = (1.f - o2) * i2;
    float tmin = fmaxf(fmaxf(fminf(a0, b0), fminf(a1, b1)), fminf(a2, b2));
    float tmax = fminf(fminf(fmaxf(a0, b0), fmaxf(a1, b1)), fmaxf(a2, b2));
    nearv = fmaxf(tmin, 0.05f);
    farv = (tmax < nearv) ? (nearv + 1e-2f) : tmax;
  }
  const float span = farv - nearv;
  const float sd = span * (1.f / 64.f);

  // ---- coarse pass ----
  const float zi = zcoarse(nearv, span, lane);
  float cx = fminf(fmaxf(fmaf(d0, zi, o0), -1.f), 1.f);
  float cy = fminf(fmaxf(fmaf(d1, zi, o1), -1.f), 1.f);
  float cz = fminf(fmaxf(fmaf(d2, zi, o2), -1.f), 1.f);
  float sraw = density_pass(pk, Xd, Xc, lane, g, c, cx, cy, cz, tf, tLoF, bd2g, 0);
  const float sigma = __expf(sraw);

  // ---- coarse compositing -> cdf (registers; shfl for +-1 lane) ----
  float cdfS;
  {
    const float znext = __shfl_down(zi, 1, 64);
    const float cdelta = (lane < 63) ? (znext - zi) : sd;
    const float calpha = 1.f - __expf(-cdelta * sigma);
    float T = 1.f - calpha + 1e-15f;
    float Pincl = scan_mul_dpp(T);
    float Pexcl = __shfl_up(Pincl, 1, 64);
    if (lane == 0) Pexcl = 1.f;
    float wgt = calpha * Pexcl;
    float v = (lane >= 1 && lane <= 62) ? (wgt + 1e-5f) : 0.f;
    float S = scan_add_dpp(v);
    cdfS = S * fast_rcp(readlane63(S));  // cdf[lane]; lane0=0
  }

  // ---- inverse-CDF resampling (register shfl search, bins analytic) ----
  // range 63 -> 64 outcomes -> 6 probes suffice.
  float nzv;
  {
    const float u = ((float)lane + 0.5f) * 0.015625f;
    int lo = 0, hi = 63;
#pragma unroll
    for (int it = 0; it < 6; ++it) {  // fixed trip: uniform exec for shfl
      int mid = (lo + hi) >> 1;
      float v = __shfl(cdfS, mid, 64);
      if (lo < hi) { if (v <= u) lo = mid + 1; else hi = mid; }
    }
    int below = lo - 1;                 // lo>=1 (cdf[0]=0 <= u always)
    int above = (lo < 62) ? lo : 62;
    float c0 = __shfl(cdfS, below, 64);
    float c1 = __shfl(cdfS, above, 64);
    float b0 = 0.5f * (zcoarse(nearv, span, below) + zcoarse(nearv, span, below + 1));
    float b1 = 0.5f * (zcoarse(nearv, span, above) + zcoarse(nearv, span, above + 1));
    float dn = c1 - c0;
    dn = (dn < 1e-5f) ? 1.f : dn;
    nzv = fmaf((u - c0) * fast_rcp(dn), (b1 - b0), b0);
  }

  // ---- fine pass ----
  float fx = fminf(fmaxf(fmaf(d0, nzv, o0), -1.f), 1.f);
  float fy = fminf(fmaxf(fmaf(d1, nzv, o1), -1.f), 1.f);
  float fz = fminf(fmaxf(fmaf(d2, nzv, o2), -1.f), 1.f);
  float nsraw = density_pass(pk, Xd, Xc, lane, g, c, fx, fy, fz, tf, tLoF, bd2g, 64);
  const float nsigma = __expf(nsraw);
  FENCE;

  // ---- stable-merge ranks ----
  // r1: shfl binary search over fine z (data-dependent; 65 outcomes -> 7 probes)
  int r1, r2;
  {
    int lo = 0, hi = 64;
#pragma unroll
    for (int it = 0; it < 7; ++it) {  // 7 = ceil(log2(65))
      int mid = (lo + hi) >> 1;
      float v = __shfl(nzv, mid, 64);
      if (lo < hi) { if (v < zi) lo = mid + 1; else hi = mid; }
    }
    r1 = lane + lo;
  }
  // r2: coarse grid is ANALYTIC -> arithmetic estimate + exact-predicate
  // verification (+-2 covers estimate error; predicate monotone in m).
  {
    float t = (nzv - nearv) * fast_rcp(span) * 63.f;
    int lo = (int)fminf(fmaxf(t, 0.f), 64.f);
    if (lo < 64 && zcoarse(nearv, span, lo) <= nzv) ++lo;
    if (lo < 64 && zcoarse(nearv, span, lo) <= nzv) ++lo;
    if (lo > 0 && zcoarse(nearv, span, lo - 1) > nzv) --lo;
    if (lo > 0 && zcoarse(nearv, span, lo - 1) > nzv) --lo;
    r2 = lane + lo;
  }
  // Xd is dead from here; zs/ss overlay it.
  FENCE;
  zsl[r1] = zi;  ssl[r1] = sigma;
  zsl[r2] = nzv; ssl[r2] = nsigma;
  FENCE;

  // ---- composite over 128 sorted samples (DPP scans; weights in registers) --
  float w0, w1, wsum;
  {
    float z0 = zsl[lane];
    float z0n = zsl[lane + 1];
    float z1 = zsl[lane + 64];
    float dl0 = z0n - z0;
    float dl1 = (lane < 63) ? (zsl[lane + 65] - z1) : sd;
    float al0 = 1.f - __expf(-dl0 * ssl[lane]);
    float al1 = 1.f - __expf(-dl1 * ssl[lane + 64]);
    float T0 = 1.f - al0 + 1e-15f;
    float T1 = 1.f - al1 + 1e-15f;
    float P0 = scan_mul_dpp(T0);
    float P1 = scan_mul_dpp(T1);
    float prodLo = readlane63(P0);
    float e0 = __shfl_up(P0, 1, 64);
    float e1 = __shfl_up(P1, 1, 64);
    if (lane == 0) { e0 = 1.f; e1 = 1.f; }
    w0 = al0 * e0;
    w1 = al1 * prodLo * e1;
    wsum = red_add_dpp(w0 + w1);  // valid on lane 63
  }

  // ---- weights back in unmerged order via shfl (uniform exec) ----
  float wlo = __shfl(w0, r1 & 63, 64);
  float whi = __shfl(w1, r1 & 63, 64);
  const float wc = (r1 < 64) ? wlo : whi;
  wlo = __shfl(w0, r2 & 63, 64);
  whi = __shfl(w1, r2 & 63, 64);
  const float wf = (r2 < 64) ? wlo : whi;

  // ---- color MLP: BRANCHLESS across all 8 tiles (full cross-tile ILP) ----
  // Per-sample wgt>1e-4 predicate preserved exactly (reference semantics);
  // the per-16-tile skip was only an optimization and blocked pipelining.
  bf16x8 CA[4];
#pragma unroll
  for (int m = 0; m < 4; ++m) CA[m] = *(const bf16x8*)(pk + 3072 + m * 512 + lane * 8);
  bf16x8 C2A[2];
  C2A[0] = *(const bf16x8*)(pk + 5120 + lane * 8);
  C2A[1] = *(const bf16x8*)(pk + 5120 + 512 + lane * 8);
  const float bc20 = bc2g[0], bc21 = bc2g[1], bc22 = bc2g[2];
  const bf16x8 bD = pack_b(cvt2(d0, d1), cvt2(d2, 1.0f), 0u, 0u);  // k16-19: d,1.0
  const bf16x8 bZ = pack_b(0u, 0u, 0u, 0u);
  const int xoffs = (g < 2) ? 8 * g : 0;

  float cr = 0.f, cgr = 0.f, cb = 0.f;
#pragma unroll
  for (int half = 0; half < 2; ++half) {
    const float wcf = half ? wf : wc;
#pragma unroll
    for (int n = 0; n < 4; ++n) {
      float wgt = __shfl(wcf, 16 * n + c, 64);  // uniform exec
      bf16x8 ld = *(const bf16x8*)&Xc[(64 * half + 16 * n + c) * 16 + xoffs];
      bf16x8 V = (g < 2) ? ld : ((g == 2) ? bD : bZ);
      f32x4 a[4];
#pragma unroll
      for (int m = 0; m < 4; ++m) {
        a[m] = (f32x4){0.f, 0.f, 0.f, 0.f};
        a[m] = __builtin_amdgcn_mfma_f32_16x16x32_bf16(CA[m], V, a[m], 0, 0, 0);
      }
      f32x4 oc = (f32x4){0.f, 0.f, 0.f, 0.f};
#pragma unroll
      for (int kt = 0; kt < 2; ++kt) {
        bf16x8 Bh = pack_b(cvtr(a[2 * kt][0], a[2 * kt][1]),
                           cvtr(a[2 * kt][2], a[2 * kt][3]),
                           cvtr(a[2 * kt + 1][0], a[2 * kt + 1][1]),
                           cvtr(a[2 * kt + 1][2], a[2 * kt + 1][3]));
        oc = __builtin_amdgcn_mfma_f32_16x16x32_bf16(C2A[kt], Bh, oc, 0, 0, 0);
      }
      if (g == 0 && wgt > 1e-4f) {
        cr  += wgt * fast_rcp(1.f + __expf(-(oc[0] + bc20)));
        cgr += wgt * fast_rcp(1.f + __expf(-(oc[1] + bc21)));
        cb  += wgt * fast_rcp(1.f + __expf(-(oc[2] + bc22)));
      }
    }
  }

  cr = red_add_dpp(cr);
  cgr = red_add_dpp(cgr);
  cb = red_add_dpp(cb);

  if (lane == 63) {  // reductions land on lane 63
    const float rem = 1.f - wsum;
    out[ray * 3 + 0] = cr + rem * bg[0];
    out[ray * 3 + 1] = cgr + rem * bg[1];
    out[ray * 3 + 2] = cb + rem * bg[2];
  }
}

extern "C" void kernel_launch(void* const* d_in, const int* in_sizes, int n_in,
                              void* d_out, int out_size, void* d_ws, size_t ws_size,
                              hipStream_t stream) {
  const float* rays_o = (const float*)d_in[0];
  const float* rays_d = (const float*)d_in[1];
  const float* time_p = (const float*)d_in[2];
  const float* bg     = (const float*)d_in[3];
  const float* Wd1    = (const float*)d_in[4];
  const float* bd1    = (const float*)d_in[5];
  const float* Wd2    = (const float*)d_in[6];
  const float* bd2    = (const float*)d_in[7];
  const float* Wc1    = (const float*)d_in[8];
  const float* bc1    = (const float*)d_in[9];
  const float* Wc2    = (const float*)d_in[10];
  const float* bc2    = (const float*)d_in[11];

  short* pk = (short*)d_ws;  // 12 KiB packed weight fragments
  pack_weights<<<1, 64, 0, stream>>>(Wd1, bd1, Wd2, Wc1, bc1, Wc2, pk);
  nerf_render<<<NRAYS, 64, 0, stream>>>(rays_o, rays_d, time_p, bg, bd2, bc2, pk,
                                        (float*)d_out);
}